// Round 1
// baseline (539.405 us; speedup 1.0000x reference)
//
#include <hip/hip_runtime.h>
#include <cmath>

#define B   64
#define NM  64
#define DM  6
#define FA  37
#define FB  6
#define NP  512
#define DP  12
#define FPD 480
#define HM  128
#define HP  128

// ---------------- ws layout (floats) ----------------
static const size_t OFF_BOND = 0;                               // B*NM*FB    = 24576
static const size_t OFF_A1   = OFF_BOND + (size_t)B*NM*FB;      // B*NM*128   = 524288
static const size_t OFF_A2   = OFF_A1   + (size_t)B*NM*128;     // B*NM*128
static const size_t OFF_FPM  = OFF_A2   + (size_t)B*NM*128;     // B*128
static const size_t OFF_FPP  = OFF_FPM  + (size_t)B*128;        // B*128
static const size_t OFF_P1   = OFF_FPP  + (size_t)B*128;        // B*NP*200
static const size_t OFF_P2   = OFF_P1   + (size_t)B*NP*200;     // B*NP*100
// total = 10,919,936 floats = 43.7 MB

// ---------------- molecule bond sum: [B,NM,DM,FB] -> [B,NM,FB] ----------------
__global__ void k_bondsum(const float* __restrict__ bonds, float* __restrict__ bond_sum) {
    int idx = blockIdx.x * blockDim.x + threadIdx.x;
    if (idx >= B * NM * FB) return;
    int f = idx % FB, bn = idx / FB;
    float s = 0.f;
    #pragma unroll
    for (int d = 0; d < DM; ++d) s += bonds[(bn * DM + d) * FB + f];
    bond_sum[idx] = s;
}

// ---------------- molecule GraphConv 1: in 43 -> 128, relu ----------------
__global__ __launch_bounds__(128) void k_mol1(
        const float* __restrict__ atoms, const int* __restrict__ edges,
        const float* __restrict__ bond_sum,
        const float* __restrict__ W, const float* __restrict__ bias,
        float* __restrict__ out) {
    int bn = blockIdx.x, b = bn >> 6, tid = threadIdx.x;
    __shared__ float s[43];
    __shared__ int e[DM];
    if (tid < DM) e[tid] = edges[bn * DM + tid];
    __syncthreads();
    if (tid < FA) {
        float v = atoms[bn * FA + tid];
        #pragma unroll
        for (int d = 0; d < DM; ++d) v += atoms[(b * NM + e[d]) * FA + tid];
        s[tid] = v;
    } else if (tid < FA + FB) {
        s[tid] = bond_sum[bn * FB + (tid - FA)];
    }
    __syncthreads();
    float acc = bias[tid];
    for (int k = 0; k < FA + FB; ++k) acc = fmaf(s[k], W[k * 128 + tid], acc);
    out[bn * 128 + tid] = fmaxf(acc, 0.f);
}

// ---------------- molecule GraphConv 2: in 134 -> 128, relu ----------------
__global__ __launch_bounds__(128) void k_mol2(
        const float* __restrict__ a1, const int* __restrict__ edges,
        const float* __restrict__ bond_sum,
        const float* __restrict__ W, const float* __restrict__ bias,
        float* __restrict__ out) {
    int bn = blockIdx.x, b = bn >> 6, tid = threadIdx.x;
    __shared__ float s[134];
    __shared__ int e[DM];
    if (tid < DM) e[tid] = edges[bn * DM + tid];
    __syncthreads();
    float v = a1[bn * 128 + tid];
    #pragma unroll
    for (int d = 0; d < DM; ++d) v += a1[(b * NM + e[d]) * 128 + tid];
    s[tid] = v;
    if (tid < FB) s[128 + tid] = bond_sum[bn * FB + tid];
    __syncthreads();
    float acc = bias[tid];
    for (int k = 0; k < 134; ++k) acc = fmaf(s[k], W[k * 128 + tid], acc);
    out[bn * 128 + tid] = fmaxf(acc, 0.f);
}

// ---------------- molecule GraphOutput: tanh(cat[a2,bond]@Wo+bo) summed over atoms ----------------
__global__ __launch_bounds__(128) void k_molout(
        const float* __restrict__ a2, const float* __restrict__ bond_sum,
        const float* __restrict__ W, const float* __restrict__ bias,
        float* __restrict__ fpm) {
    int b = blockIdx.y, g = blockIdx.x, tid = threadIdx.x;
    int n0 = g * 8;
    __shared__ float s[8 * 134];
    for (int t = tid; t < 8 * 134; t += 128) {
        int r = t / 134, k = t % 134, n = n0 + r;
        s[t] = (k < 128) ? a2[(b * NM + n) * 128 + k]
                         : bond_sum[(b * NM + n) * FB + (k - 128)];
    }
    __syncthreads();
    float sum = 0.f;
    for (int r = 0; r < 8; ++r) {
        float acc = bias[tid];
        for (int k = 0; k < 134; ++k) acc = fmaf(s[r * 134 + k], W[k * 128 + tid], acc);
        sum += tanhf(acc);
    }
    atomicAdd(&fpm[b * 128 + tid], sum);
}

// ---------------- protein GraphConv 1 (fused gather): [480]->[200], relu ----------------
// block: 256 thr = 64 n-threads (4 cols each) x 4 m-threads (4 rows each); tile 16 rows
__global__ __launch_bounds__(256) void k_p1(
        const float* __restrict__ atoms, const int* __restrict__ edges,
        const float* __restrict__ W, const float* __restrict__ bias,
        float* __restrict__ out) {
    int b = blockIdx.y, mt = blockIdx.x, tid = threadIdx.x;
    int n0 = mt * 16;
    __shared__ __align__(16) float st[FPD * 20];   // pitch 20: float4-aligned reads
    __shared__ int e[16 * DP];
    if (tid < 16 * DP) {
        int r = tid / DP, d = tid % DP;
        e[tid] = edges[(b * NP + n0 + r) * DP + d];
    }
    __syncthreads();
    const float* base = atoms + (size_t)b * NP * FPD;
    for (int t = tid; t < 16 * FPD; t += 256) {
        int k = t % FPD, r = t / FPD;
        float v = base[(n0 + r) * FPD + k];
        #pragma unroll
        for (int d = 0; d < DP; ++d) v += base[e[r * DP + d] * FPD + k];
        st[k * 20 + r] = v;
    }
    __syncthreads();
    int nt = tid & 63, mtt = tid >> 6;
    int j0 = nt * 4, r0 = mtt * 4;
    if (j0 < 200) {
        float acc[4][4] = {};
        #pragma unroll 4
        for (int k = 0; k < FPD; ++k) {
            float4 s4 = *(const float4*)&st[k * 20 + r0];
            float4 w4 = *(const float4*)&W[k * 200 + j0];
            float sa[4] = {s4.x, s4.y, s4.z, s4.w};
            float wa[4] = {w4.x, w4.y, w4.z, w4.w};
            #pragma unroll
            for (int m = 0; m < 4; ++m)
                #pragma unroll
                for (int n = 0; n < 4; ++n)
                    acc[m][n] = fmaf(sa[m], wa[n], acc[m][n]);
        }
        float4 bb = *(const float4*)&bias[j0];
        float ba[4] = {bb.x, bb.y, bb.z, bb.w};
        #pragma unroll
        for (int m = 0; m < 4; ++m) {
            float4 o;
            o.x = fmaxf(acc[m][0] + ba[0], 0.f);
            o.y = fmaxf(acc[m][1] + ba[1], 0.f);
            o.z = fmaxf(acc[m][2] + ba[2], 0.f);
            o.w = fmaxf(acc[m][3] + ba[3], 0.f);
            *(float4*)&out[((size_t)(b * NP) + n0 + r0 + m) * 200 + j0] = o;
        }
    }
}

// ---------------- protein GraphConv 2 (fused gather): [200]->[100], relu ----------------
// block: 256 thr = 32 n-threads (4 cols) x 8 m-threads (2 rows); tile 16 rows
__global__ __launch_bounds__(256) void k_p2(
        const float* __restrict__ p1, const int* __restrict__ edges,
        const float* __restrict__ W, const float* __restrict__ bias,
        float* __restrict__ out) {
    int b = blockIdx.y, mt = blockIdx.x, tid = threadIdx.x;
    int n0 = mt * 16;
    __shared__ __align__(16) float st[200 * 20];
    __shared__ int e[16 * DP];
    if (tid < 16 * DP) {
        int r = tid / DP, d = tid % DP;
        e[tid] = edges[(b * NP + n0 + r) * DP + d];
    }
    __syncthreads();
    const float* base = p1 + (size_t)b * NP * 200;
    for (int t = tid; t < 16 * 200; t += 256) {
        int k = t % 200, r = t / 200;
        float v = base[(n0 + r) * 200 + k];
        #pragma unroll
        for (int d = 0; d < DP; ++d) v += base[e[r * DP + d] * 200 + k];
        st[k * 20 + r] = v;
    }
    __syncthreads();
    int nt = tid & 31, mtt = tid >> 5;
    int j0 = nt * 4, r0 = mtt * 2;
    if (j0 < 100) {
        float acc[2][4] = {};
        #pragma unroll 4
        for (int k = 0; k < 200; ++k) {
            float2 s2 = *(const float2*)&st[k * 20 + r0];
            float4 w4 = *(const float4*)&W[k * 100 + j0];
            float sa[2] = {s2.x, s2.y};
            float wa[4] = {w4.x, w4.y, w4.z, w4.w};
            #pragma unroll
            for (int m = 0; m < 2; ++m)
                #pragma unroll
                for (int n = 0; n < 4; ++n)
                    acc[m][n] = fmaf(sa[m], wa[n], acc[m][n]);
        }
        float4 bb = *(const float4*)&bias[j0];
        float ba[4] = {bb.x, bb.y, bb.z, bb.w};
        #pragma unroll
        for (int m = 0; m < 2; ++m) {
            float4 o;
            o.x = fmaxf(acc[m][0] + ba[0], 0.f);
            o.y = fmaxf(acc[m][1] + ba[1], 0.f);
            o.z = fmaxf(acc[m][2] + ba[2], 0.f);
            o.w = fmaxf(acc[m][3] + ba[3], 0.f);
            *(float4*)&out[((size_t)(b * NP) + n0 + r0 + m) * 100 + j0] = o;
        }
    }
}

// ---------------- protein GraphOutput: tanh(p2@Wop+bop) summed over 512 atoms ----------------
// block 128 thr (thread = output col), 16 atoms/block
__global__ __launch_bounds__(128) void k_pout(
        const float* __restrict__ p2, const float* __restrict__ W,
        const float* __restrict__ bias, float* __restrict__ fpp) {
    int b = blockIdx.y, g = blockIdx.x, tid = threadIdx.x;
    int n0 = g * 16;
    __shared__ __align__(16) float st[100 * 20];
    const float* base = p2 + (size_t)b * NP * 100;
    for (int t = tid; t < 16 * 100; t += 128) {
        int k = t % 100, r = t / 100;
        st[k * 20 + r] = base[(n0 + r) * 100 + k];
    }
    __syncthreads();
    float acc[16] = {};
    for (int k = 0; k < 100; ++k) {
        float w = W[k * 128 + tid];
        float4 s0 = *(const float4*)&st[k * 20 + 0];
        float4 s1 = *(const float4*)&st[k * 20 + 4];
        float4 s2 = *(const float4*)&st[k * 20 + 8];
        float4 s3 = *(const float4*)&st[k * 20 + 12];
        acc[0]  = fmaf(s0.x, w, acc[0]);  acc[1]  = fmaf(s0.y, w, acc[1]);
        acc[2]  = fmaf(s0.z, w, acc[2]);  acc[3]  = fmaf(s0.w, w, acc[3]);
        acc[4]  = fmaf(s1.x, w, acc[4]);  acc[5]  = fmaf(s1.y, w, acc[5]);
        acc[6]  = fmaf(s1.z, w, acc[6]);  acc[7]  = fmaf(s1.w, w, acc[7]);
        acc[8]  = fmaf(s2.x, w, acc[8]);  acc[9]  = fmaf(s2.y, w, acc[9]);
        acc[10] = fmaf(s2.z, w, acc[10]); acc[11] = fmaf(s2.w, w, acc[11]);
        acc[12] = fmaf(s3.x, w, acc[12]); acc[13] = fmaf(s3.y, w, acc[13]);
        acc[14] = fmaf(s3.z, w, acc[14]); acc[15] = fmaf(s3.w, w, acc[15]);
    }
    float bj = bias[tid], sum = 0.f;
    #pragma unroll
    for (int r = 0; r < 16; ++r) sum += tanhf(acc[r] + bj);
    atomicAdd(&fpp[b * 128 + tid], sum);
}

// ---------------- FC stack: [256]->100->100->1, sigmoid ----------------
__global__ __launch_bounds__(128) void k_fc(
        const float* __restrict__ fpm, const float* __restrict__ fpp,
        const float* __restrict__ Wf1, const float* __restrict__ bf1,
        const float* __restrict__ Wf2, const float* __restrict__ bf2,
        const float* __restrict__ Wout, const float* __restrict__ bout,
        float* __restrict__ out) {
    int b = blockIdx.x, tid = threadIdx.x;
    __shared__ float fp[256], h1[100], h2[100];
    fp[tid]       = fpm[b * 128 + tid];
    fp[tid + 128] = fpp[b * 128 + tid];
    __syncthreads();
    if (tid < 100) {
        float acc = bf1[tid];
        for (int k = 0; k < 256; ++k) acc = fmaf(fp[k], Wf1[k * 100 + tid], acc);
        h1[tid] = acc;
    }
    __syncthreads();
    if (tid < 100) {
        float acc = bf2[tid];
        for (int k = 0; k < 100; ++k) acc = fmaf(h1[k], Wf2[k * 100 + tid], acc);
        h2[tid] = acc;
    }
    __syncthreads();
    if (tid < 64) {
        float v = h2[tid] * Wout[tid];
        if (tid + 64 < 100) v += h2[tid + 64] * Wout[tid + 64];
        #pragma unroll
        for (int off = 32; off > 0; off >>= 1) v += __shfl_down(v, off);
        if (tid == 0) out[b] = 1.f / (1.f + expf(-(v + bout[0])));
    }
}

extern "C" void kernel_launch(void* const* d_in, const int* in_sizes, int n_in,
                              void* d_out, int out_size, void* d_ws, size_t ws_size,
                              hipStream_t stream) {
    const float* m_atoms = (const float*)d_in[0];
    const float* m_bonds = (const float*)d_in[1];
    const int*   m_edges = (const int*)  d_in[2];
    const float* p_atoms = (const float*)d_in[3];
    const int*   p_edges = (const int*)  d_in[4];
    const float* W1   = (const float*)d_in[5];  const float* b1   = (const float*)d_in[6];
    const float* W2   = (const float*)d_in[7];  const float* b2   = (const float*)d_in[8];
    const float* Wp1  = (const float*)d_in[9];  const float* bp1  = (const float*)d_in[10];
    const float* Wp2  = (const float*)d_in[11]; const float* bp2  = (const float*)d_in[12];
    const float* Wo   = (const float*)d_in[13]; const float* bo   = (const float*)d_in[14];
    const float* Wop  = (const float*)d_in[15]; const float* bop  = (const float*)d_in[16];
    const float* Wf1  = (const float*)d_in[17]; const float* bf1  = (const float*)d_in[18];
    const float* Wf2  = (const float*)d_in[19]; const float* bf2  = (const float*)d_in[20];
    const float* Wout = (const float*)d_in[21]; const float* bout = (const float*)d_in[22];

    float* ws       = (float*)d_ws;
    float* bond_sum = ws + OFF_BOND;
    float* a1       = ws + OFF_A1;
    float* a2       = ws + OFF_A2;
    float* fpm      = ws + OFF_FPM;
    float* fpp      = ws + OFF_FPP;
    float* p1       = ws + OFF_P1;
    float* p2       = ws + OFF_P2;

    // zero the atomic fingerprint accumulators (fpm | fpp contiguous)
    hipMemsetAsync(fpm, 0, (size_t)2 * B * 128 * sizeof(float), stream);

    k_bondsum<<<dim3((B * NM * FB + 255) / 256), 256, 0, stream>>>(m_bonds, bond_sum);
    k_mol1  <<<dim3(B * NM), 128, 0, stream>>>(m_atoms, m_edges, bond_sum, W1, b1, a1);
    k_mol2  <<<dim3(B * NM), 128, 0, stream>>>(a1, m_edges, bond_sum, W2, b2, a2);
    k_molout<<<dim3(NM / 8, B), 128, 0, stream>>>(a2, bond_sum, Wo, bo, fpm);
    k_p1    <<<dim3(NP / 16, B), 256, 0, stream>>>(p_atoms, p_edges, Wp1, bp1, p1);
    k_p2    <<<dim3(NP / 16, B), 256, 0, stream>>>(p1, p_edges, Wp2, bp2, p2);
    k_pout  <<<dim3(NP / 16, B), 128, 0, stream>>>(p2, Wop, bop, fpp);
    k_fc    <<<dim3(B), 128, 0, stream>>>(fpm, fpp, Wf1, bf1, Wf2, bf2, Wout, bout, (float*)d_out);
}

// Round 3
// 429.545 us; speedup vs baseline: 1.2558x; 1.2558x over previous
//
#include <hip/hip_runtime.h>
#include <cmath>

#define B   64
#define NM  64
#define DM  6
#define FA  37
#define FB  6
#define NP  512
#define DP  12
#define FPD 480
#define HM  128
#define HP  128

// ---------------- ws layout (floats) ----------------
static const size_t OFF_BOND = 0;                               // B*NM*FB
static const size_t OFF_A1   = OFF_BOND + (size_t)B*NM*FB;      // B*NM*128
static const size_t OFF_A2   = OFF_A1   + (size_t)B*NM*128;     // B*NM*128
static const size_t OFF_FPM  = OFF_A2   + (size_t)B*NM*128;     // B*128
static const size_t OFF_FPP  = OFF_FPM  + (size_t)B*128;        // B*128
static const size_t OFF_Z    = OFF_FPP  + (size_t)B*128;        // B*NP*200 (Z1, later Z2 [100-wide])
static const size_t OFF_P    = OFF_Z    + (size_t)B*NP*200;     // B*NP*200 (p1, later p2 [100-wide])
// total = 14,196,736 floats = 56.8 MB

__device__ __forceinline__ float4 f4add(float4 a, float4 b) {
    return make_float4(a.x + b.x, a.y + b.y, a.z + b.z, a.w + b.w);
}

// ---------------- molecule bond sum: [B,NM,DM,FB] -> [B,NM,FB] ----------------
__global__ void k_bondsum(const float* __restrict__ bonds, float* __restrict__ bond_sum) {
    int idx = blockIdx.x * blockDim.x + threadIdx.x;
    if (idx >= B * NM * FB) return;
    int f = idx % FB, bn = idx / FB;
    float s = 0.f;
    #pragma unroll
    for (int d = 0; d < DM; ++d) s += bonds[(bn * DM + d) * FB + f];
    bond_sum[idx] = s;
}

// ---------------- molecule GraphConv 1: in 43 -> 128, relu ----------------
__global__ __launch_bounds__(128) void k_mol1(
        const float* __restrict__ atoms, const int* __restrict__ edges,
        const float* __restrict__ bond_sum,
        const float* __restrict__ W, const float* __restrict__ bias,
        float* __restrict__ out) {
    int bn = blockIdx.x, b = bn >> 6, tid = threadIdx.x;
    __shared__ float s[43];
    __shared__ int e[DM];
    if (tid < DM) e[tid] = edges[bn * DM + tid];
    __syncthreads();
    if (tid < FA) {
        float v = atoms[bn * FA + tid];
        #pragma unroll
        for (int d = 0; d < DM; ++d) v += atoms[(b * NM + e[d]) * FA + tid];
        s[tid] = v;
    } else if (tid < FA + FB) {
        s[tid] = bond_sum[bn * FB + (tid - FA)];
    }
    __syncthreads();
    float acc = bias[tid];
    for (int k = 0; k < FA + FB; ++k) acc = fmaf(s[k], W[k * 128 + tid], acc);
    out[bn * 128 + tid] = fmaxf(acc, 0.f);
}

// ---------------- molecule GraphConv 2: in 134 -> 128, relu ----------------
__global__ __launch_bounds__(128) void k_mol2(
        const float* __restrict__ a1, const int* __restrict__ edges,
        const float* __restrict__ bond_sum,
        const float* __restrict__ W, const float* __restrict__ bias,
        float* __restrict__ out) {
    int bn = blockIdx.x, b = bn >> 6, tid = threadIdx.x;
    __shared__ float s[134];
    __shared__ int e[DM];
    if (tid < DM) e[tid] = edges[bn * DM + tid];
    __syncthreads();
    float v = a1[bn * 128 + tid];
    #pragma unroll
    for (int d = 0; d < DM; ++d) v += a1[(b * NM + e[d]) * 128 + tid];
    s[tid] = v;
    if (tid < FB) s[128 + tid] = bond_sum[bn * FB + tid];
    __syncthreads();
    float acc = bias[tid];
    for (int k = 0; k < 134; ++k) acc = fmaf(s[k], W[k * 128 + tid], acc);
    out[bn * 128 + tid] = fmaxf(acc, 0.f);
}

// ---------------- molecule GraphOutput ----------------
__global__ __launch_bounds__(128) void k_molout(
        const float* __restrict__ a2, const float* __restrict__ bond_sum,
        const float* __restrict__ W, const float* __restrict__ bias,
        float* __restrict__ fpm) {
    int b = blockIdx.y, g = blockIdx.x, tid = threadIdx.x;
    int n0 = g * 8;
    __shared__ float s[8 * 134];
    for (int t = tid; t < 8 * 134; t += 128) {
        int r = t / 134, k = t % 134, n = n0 + r;
        s[t] = (k < 128) ? a2[(b * NM + n) * 128 + k]
                         : bond_sum[(b * NM + n) * FB + (k - 128)];
    }
    __syncthreads();
    float sum = 0.f;
    for (int r = 0; r < 8; ++r) {
        float acc = bias[tid];
        for (int k = 0; k < 134; ++k) acc = fmaf(s[r * 134 + k], W[k * 128 + tid], acc);
        sum += tanhf(acc);
    }
    atomicAdd(&fpm[b * 128 + tid], sum);
}

// ---------------- dense GEMM 1: Z1 = p_atoms @ Wp1  [32768,480]x[480,200] ----------------
// block 256: 64 n-threads (4 cols, nt<50 active) x 4 m-threads (8 rows) -> 32x200 tile
__global__ __launch_bounds__(256) void k_zp1(
        const float* __restrict__ A, const float* __restrict__ W,
        float* __restrict__ Z) {
    int tid = threadIdx.x;
    int n0 = blockIdx.x * 32;
    __shared__ __align__(16) float st[32 * 484];   // [r][k], pitch 484 (mult of 4)
    for (int t = tid; t < 32 * 120; t += 256) {
        int r = t / 120, kq = t % 120;
        float4 a4 = *(const float4*)&A[(size_t)(n0 + r) * FPD + kq * 4];
        *(float4*)&st[r * 484 + kq * 4] = a4;
    }
    __syncthreads();
    int nt = tid & 63, mt = tid >> 6;
    int j0 = nt * 4, r0 = mt * 8;
    if (nt < 50) {
        float acc[8][4] = {};
        for (int k0 = 0; k0 < FPD; k0 += 4) {
            float4 w0 = *(const float4*)&W[(k0 + 0) * 200 + j0];
            float4 w1 = *(const float4*)&W[(k0 + 1) * 200 + j0];
            float4 w2 = *(const float4*)&W[(k0 + 2) * 200 + j0];
            float4 w3 = *(const float4*)&W[(k0 + 3) * 200 + j0];
            #pragma unroll
            for (int m = 0; m < 8; ++m) {
                float4 a4 = *(const float4*)&st[(r0 + m) * 484 + k0];
                acc[m][0] = fmaf(a4.x, w0.x, acc[m][0]);
                acc[m][1] = fmaf(a4.x, w0.y, acc[m][1]);
                acc[m][2] = fmaf(a4.x, w0.z, acc[m][2]);
                acc[m][3] = fmaf(a4.x, w0.w, acc[m][3]);
                acc[m][0] = fmaf(a4.y, w1.x, acc[m][0]);
                acc[m][1] = fmaf(a4.y, w1.y, acc[m][1]);
                acc[m][2] = fmaf(a4.y, w1.z, acc[m][2]);
                acc[m][3] = fmaf(a4.y, w1.w, acc[m][3]);
                acc[m][0] = fmaf(a4.z, w2.x, acc[m][0]);
                acc[m][1] = fmaf(a4.z, w2.y, acc[m][1]);
                acc[m][2] = fmaf(a4.z, w2.z, acc[m][2]);
                acc[m][3] = fmaf(a4.z, w2.w, acc[m][3]);
                acc[m][0] = fmaf(a4.w, w3.x, acc[m][0]);
                acc[m][1] = fmaf(a4.w, w3.y, acc[m][1]);
                acc[m][2] = fmaf(a4.w, w3.z, acc[m][2]);
                acc[m][3] = fmaf(a4.w, w3.w, acc[m][3]);
            }
        }
        #pragma unroll
        for (int m = 0; m < 8; ++m)
            *(float4*)&Z[(size_t)(n0 + r0 + m) * 200 + j0] =
                make_float4(acc[m][0], acc[m][1], acc[m][2], acc[m][3]);
    }
}

// ---------------- gather 1: p1 = relu(Z1[n] + sum_d Z1[e] + bp1), width 200 ----------------
__global__ __launch_bounds__(256) void k_ga1(
        const float* __restrict__ Z, const int* __restrict__ edges,
        const float* __restrict__ bias, float* __restrict__ out) {
    int bid = blockIdx.x;                      // 2048 = 64 b x 32 tiles, XCD-swizzled
    int x = bid & 7, j = bid >> 3;
    int b = (j >> 5) * 8 + x, tile = j & 31;
    int n0 = tile * 16, tid = threadIdx.x;
    __shared__ int e[16 * DP];
    if (tid < 16 * DP)
        e[tid] = edges[(b * NP + n0 + tid / DP) * DP + tid % DP];
    __syncthreads();
    const float4* Zb = (const float4*)(Z + (size_t)b * NP * 200);
    float4* ob = (float4*)(out + (size_t)b * NP * 200);
    const float4* b4 = (const float4*)bias;
    for (int idx = tid; idx < 16 * 50; idx += 256) {
        int r = idx / 50, c = idx % 50;
        float4 v = Zb[(n0 + r) * 50 + c];
        #pragma unroll
        for (int d = 0; d < DP; ++d) v = f4add(v, Zb[e[r * DP + d] * 50 + c]);
        v = f4add(v, b4[c]);
        ob[(n0 + r) * 50 + c] = make_float4(fmaxf(v.x, 0.f), fmaxf(v.y, 0.f),
                                            fmaxf(v.z, 0.f), fmaxf(v.w, 0.f));
    }
}

// ---------------- dense GEMM 2: Z2 = p1 @ Wp2  [32768,200]x[200,100] ----------------
// block 256: 64 n-threads (2 cols, nt<50) x 4 m-threads (8 rows) -> 32x100 tile
__global__ __launch_bounds__(256) void k_zp2(
        const float* __restrict__ A, const float* __restrict__ W,
        float* __restrict__ Z) {
    int tid = threadIdx.x;
    int n0 = blockIdx.x * 32;
    __shared__ __align__(16) float st[32 * 204];
    for (int t = tid; t < 32 * 50; t += 256) {
        int r = t / 50, kq = t % 50;
        float4 a4 = *(const float4*)&A[(size_t)(n0 + r) * 200 + kq * 4];
        *(float4*)&st[r * 204 + kq * 4] = a4;
    }
    __syncthreads();
    int nt = tid & 63, mt = tid >> 6;
    int j0 = nt * 2, r0 = mt * 8;
    if (nt < 50) {
        float acc[8][2] = {};
        for (int k0 = 0; k0 < 200; k0 += 4) {
            float2 w0 = *(const float2*)&W[(k0 + 0) * 100 + j0];
            float2 w1 = *(const float2*)&W[(k0 + 1) * 100 + j0];
            float2 w2 = *(const float2*)&W[(k0 + 2) * 100 + j0];
            float2 w3 = *(const float2*)&W[(k0 + 3) * 100 + j0];
            #pragma unroll
            for (int m = 0; m < 8; ++m) {
                float4 a4 = *(const float4*)&st[(r0 + m) * 204 + k0];
                acc[m][0] = fmaf(a4.x, w0.x, acc[m][0]);
                acc[m][1] = fmaf(a4.x, w0.y, acc[m][1]);
                acc[m][0] = fmaf(a4.y, w1.x, acc[m][0]);
                acc[m][1] = fmaf(a4.y, w1.y, acc[m][1]);
                acc[m][0] = fmaf(a4.z, w2.x, acc[m][0]);
                acc[m][1] = fmaf(a4.z, w2.y, acc[m][1]);
                acc[m][0] = fmaf(a4.w, w3.x, acc[m][0]);
                acc[m][1] = fmaf(a4.w, w3.y, acc[m][1]);
            }
        }
        #pragma unroll
        for (int m = 0; m < 8; ++m)
            *(float2*)&Z[(size_t)(n0 + r0 + m) * 100 + j0] =
                make_float2(acc[m][0], acc[m][1]);
    }
}

// ---------------- gather 2: p2 = relu(Z2[n] + sum_d Z2[e] + bp2), width 100 ----------------
__global__ __launch_bounds__(256) void k_ga2(
        const float* __restrict__ Z, const int* __restrict__ edges,
        const float* __restrict__ bias, float* __restrict__ out) {
    int bid = blockIdx.x;
    int x = bid & 7, j = bid >> 3;
    int b = (j >> 5) * 8 + x, tile = j & 31;
    int n0 = tile * 16, tid = threadIdx.x;
    __shared__ int e[16 * DP];
    if (tid < 16 * DP)
        e[tid] = edges[(b * NP + n0 + tid / DP) * DP + tid % DP];
    __syncthreads();
    const float4* Zb = (const float4*)(Z + (size_t)b * NP * 100);
    float4* ob = (float4*)(out + (size_t)b * NP * 100);
    const float4* b4 = (const float4*)bias;
    for (int idx = tid; idx < 16 * 25; idx += 256) {
        int r = idx / 25, c = idx % 25;
        float4 v = Zb[(n0 + r) * 25 + c];
        #pragma unroll
        for (int d = 0; d < DP; ++d) v = f4add(v, Zb[e[r * DP + d] * 25 + c]);
        v = f4add(v, b4[c]);
        ob[(n0 + r) * 25 + c] = make_float4(fmaxf(v.x, 0.f), fmaxf(v.y, 0.f),
                                            fmaxf(v.z, 0.f), fmaxf(v.w, 0.f));
    }
}

// ---------------- protein GraphOutput: tanh(p2@Wop+bop) summed over 512 atoms ----------------
__global__ __launch_bounds__(128) void k_pout(
        const float* __restrict__ p2, const float* __restrict__ W,
        const float* __restrict__ bias, float* __restrict__ fpp) {
    int b = blockIdx.y, g = blockIdx.x, tid = threadIdx.x;
    int n0 = g * 16;
    __shared__ __align__(16) float st[100 * 20];
    const float* base = p2 + (size_t)b * NP * 100;
    for (int t = tid; t < 16 * 100; t += 128) {
        int k = t % 100, r = t / 100;
        st[k * 20 + r] = base[(n0 + r) * 100 + k];
    }
    __syncthreads();
    float acc[16] = {};
    for (int k = 0; k < 100; ++k) {
        float w = W[k * 128 + tid];
        float4 s0 = *(const float4*)&st[k * 20 + 0];
        float4 s1 = *(const float4*)&st[k * 20 + 4];
        float4 s2 = *(const float4*)&st[k * 20 + 8];
        float4 s3 = *(const float4*)&st[k * 20 + 12];
        acc[0]  = fmaf(s0.x, w, acc[0]);  acc[1]  = fmaf(s0.y, w, acc[1]);
        acc[2]  = fmaf(s0.z, w, acc[2]);  acc[3]  = fmaf(s0.w, w, acc[3]);
        acc[4]  = fmaf(s1.x, w, acc[4]);  acc[5]  = fmaf(s1.y, w, acc[5]);
        acc[6]  = fmaf(s1.z, w, acc[6]);  acc[7]  = fmaf(s1.w, w, acc[7]);
        acc[8]  = fmaf(s2.x, w, acc[8]);  acc[9]  = fmaf(s2.y, w, acc[9]);
        acc[10] = fmaf(s2.z, w, acc[10]); acc[11] = fmaf(s2.w, w, acc[11]);
        acc[12] = fmaf(s3.x, w, acc[12]); acc[13] = fmaf(s3.y, w, acc[13]);
        acc[14] = fmaf(s3.z, w, acc[14]); acc[15] = fmaf(s3.w, w, acc[15]);
    }
    float bj = bias[tid], sum = 0.f;
    #pragma unroll
    for (int r = 0; r < 16; ++r) sum += tanhf(acc[r] + bj);
    atomicAdd(&fpp[b * 128 + tid], sum);
}

// ---------------- FC stack ----------------
__global__ __launch_bounds__(128) void k_fc(
        const float* __restrict__ fpm, const float* __restrict__ fpp,
        const float* __restrict__ Wf1, const float* __restrict__ bf1,
        const float* __restrict__ Wf2, const float* __restrict__ bf2,
        const float* __restrict__ Wout, const float* __restrict__ bout,
        float* __restrict__ out) {
    int b = blockIdx.x, tid = threadIdx.x;
    __shared__ float fp[256], h1[100], h2[100];
    fp[tid]       = fpm[b * 128 + tid];
    fp[tid + 128] = fpp[b * 128 + tid];
    __syncthreads();
    if (tid < 100) {
        float acc = bf1[tid];
        for (int k = 0; k < 256; ++k) acc = fmaf(fp[k], Wf1[k * 100 + tid], acc);
        h1[tid] = acc;
    }
    __syncthreads();
    if (tid < 100) {
        float acc = bf2[tid];
        for (int k = 0; k < 100; ++k) acc = fmaf(h1[k], Wf2[k * 100 + tid], acc);
        h2[tid] = acc;
    }
    __syncthreads();
    if (tid < 64) {
        float v = h2[tid] * Wout[tid];
        if (tid + 64 < 100) v += h2[tid + 64] * Wout[tid + 64];
        #pragma unroll
        for (int off = 32; off > 0; off >>= 1) v += __shfl_down(v, off);
        if (tid == 0) out[b] = 1.f / (1.f + expf(-(v + bout[0])));
    }
}

extern "C" void kernel_launch(void* const* d_in, const int* in_sizes, int n_in,
                              void* d_out, int out_size, void* d_ws, size_t ws_size,
                              hipStream_t stream) {
    const float* m_atoms = (const float*)d_in[0];
    const float* m_bonds = (const float*)d_in[1];
    const int*   m_edges = (const int*)  d_in[2];
    const float* p_atoms = (const float*)d_in[3];
    const int*   p_edges = (const int*)  d_in[4];
    const float* W1   = (const float*)d_in[5];  const float* b1   = (const float*)d_in[6];
    const float* W2   = (const float*)d_in[7];  const float* b2   = (const float*)d_in[8];
    const float* Wp1  = (const float*)d_in[9];  const float* bp1  = (const float*)d_in[10];
    const float* Wp2  = (const float*)d_in[11]; const float* bp2  = (const float*)d_in[12];
    const float* Wo   = (const float*)d_in[13]; const float* bo   = (const float*)d_in[14];
    const float* Wop  = (const float*)d_in[15]; const float* bop  = (const float*)d_in[16];
    const float* Wf1  = (const float*)d_in[17]; const float* bf1  = (const float*)d_in[18];
    const float* Wf2  = (const float*)d_in[19]; const float* bf2  = (const float*)d_in[20];
    const float* Wout = (const float*)d_in[21]; const float* bout = (const float*)d_in[22];

    float* ws       = (float*)d_ws;
    float* bond_sum = ws + OFF_BOND;
    float* a1       = ws + OFF_A1;
    float* a2       = ws + OFF_A2;
    float* fpm      = ws + OFF_FPM;
    float* fpp      = ws + OFF_FPP;
    float* zbuf     = ws + OFF_Z;   // Z1 (200-wide), then Z2 (100-wide)
    float* pbuf     = ws + OFF_P;   // p1 (200-wide), then p2 (100-wide)

    hipMemsetAsync(fpm, 0, (size_t)2 * B * 128 * sizeof(float), stream);

    // protein path: GEMM -> gather -> GEMM -> gather -> output
    k_zp1 <<<dim3(B * NP / 32), 256, 0, stream>>>(p_atoms, Wp1, zbuf);
    k_ga1 <<<dim3(B * NP / 16), 256, 0, stream>>>(zbuf, p_edges, bp1, pbuf);
    k_zp2 <<<dim3(B * NP / 32), 256, 0, stream>>>(pbuf, Wp2, zbuf);
    k_ga2 <<<dim3(B * NP / 16), 256, 0, stream>>>(zbuf, p_edges, bp2, pbuf);
    k_pout<<<dim3(NP / 16, B), 128, 0, stream>>>(pbuf, Wop, bop, fpp);

    // molecule path
    k_bondsum<<<dim3((B * NM * FB + 255) / 256), 256, 0, stream>>>(m_bonds, bond_sum);
    k_mol1  <<<dim3(B * NM), 128, 0, stream>>>(m_atoms, m_edges, bond_sum, W1, b1, a1);
    k_mol2  <<<dim3(B * NM), 128, 0, stream>>>(a1, m_edges, bond_sum, W2, b2, a2);
    k_molout<<<dim3(NM / 8, B), 128, 0, stream>>>(a2, bond_sum, Wo, bo, fpm);

    k_fc    <<<dim3(B), 128, 0, stream>>>(fpm, fpp, Wf1, bf1, Wf2, bf2, Wout, bout, (float*)d_out);
}

// Round 4
// 351.912 us; speedup vs baseline: 1.5328x; 1.2206x over previous
//
#include <hip/hip_runtime.h>
#include <cmath>

#define B   64
#define NM  64
#define DM  6
#define FA  37
#define FB  6
#define NP  512
#define DP  12
#define FPD 480
#define HM  128
#define HP  128

typedef _Float16 half8 __attribute__((ext_vector_type(8)));
typedef float f32x4 __attribute__((ext_vector_type(4)));

// ---------------- ws layout (floats) ----------------
static const size_t OFF_BOND = 0;                               // B*NM*FB
static const size_t OFF_A1   = OFF_BOND + (size_t)B*NM*FB;      // B*NM*128
static const size_t OFF_A2   = OFF_A1   + (size_t)B*NM*128;     // B*NM*128
static const size_t OFF_FPM  = OFF_A2   + (size_t)B*NM*128;     // B*128
static const size_t OFF_FPP  = OFF_FPM  + (size_t)B*128;        // B*128
static const size_t OFF_Z    = OFF_FPP  + (size_t)B*128;        // B*NP*200 (Z1, later Z2 [100-wide])
static const size_t OFF_P    = OFF_Z    + (size_t)B*NP*200;     // B*NP*200 (p1, later p2 [100-wide])
static const size_t OFF_W16  = OFF_P    + (size_t)B*NP*200 + 256;  // fp16 weights (+256 slack for A overread)
// fp16 sub-offsets (in _Float16 units, from OFF_W16)
#define W16_WT1  0          // [224][480]
#define W16_WT2  107520     // [112][224]
#define W16_WTOP 132608     // [128][128]
#define W16_TOT  148992
// ws total = OFF_W16 + W16_TOT/2 floats ~= 57.1 MB

__device__ __forceinline__ float4 f4add(float4 a, float4 b) {
    return make_float4(a.x + b.x, a.y + b.y, a.z + b.z, a.w + b.w);
}

__device__ __forceinline__ half8 load_a_frag(const float* p) {
    float4 f0 = *(const float4*)(p);
    float4 f1 = *(const float4*)(p + 4);
    half8 h;
    h[0] = (_Float16)f0.x; h[1] = (_Float16)f0.y; h[2] = (_Float16)f0.z; h[3] = (_Float16)f0.w;
    h[4] = (_Float16)f1.x; h[5] = (_Float16)f1.y; h[6] = (_Float16)f1.z; h[7] = (_Float16)f1.w;
    return h;
}

// ---------------- weight prep: transpose + pad + fp16 ----------------
__global__ void k_prep(const float* __restrict__ Wp1, const float* __restrict__ Wp2,
                       const float* __restrict__ Wop, _Float16* __restrict__ w16) {
    int idx = blockIdx.x * 256 + threadIdx.x;
    if (idx < 224 * 480) {                       // Wt1[n][k] = Wp1[k][n], n<200
        int n = idx / 480, k = idx % 480;
        w16[idx] = (n < 200) ? (_Float16)Wp1[k * 200 + n] : (_Float16)0.f;
    } else if (idx < 224 * 480 + 112 * 224) {    // Wt2[n][k] = Wp2[k][n], n<100,k<200
        int r = idx - 224 * 480;
        int n = r / 224, k = r % 224;
        w16[idx] = (n < 100 && k < 200) ? (_Float16)Wp2[k * 100 + n] : (_Float16)0.f;
    } else if (idx < W16_TOT) {                  // Wtop[n][k] = Wop[k][n], k<100
        int r = idx - (224 * 480 + 112 * 224);
        int n = r >> 7, k = r & 127;
        w16[idx] = (k < 100) ? (_Float16)Wop[k * 128 + n] : (_Float16)0.f;
    }
}

// ---------------- MFMA GEMM 1: Z1 = p_atoms @ Wp1  [32768,480]x[480,200] ----------------
// 4 waves = 2 row x 2 col; wave-tile 32x112; block-tile 64x224; no LDS
__global__ __launch_bounds__(256) void k_zp1(
        const float* __restrict__ A, const _Float16* __restrict__ Wt,
        float* __restrict__ Z) {
    int tid = threadIdx.x, lane = tid & 63, wid = tid >> 6;
    int rw = wid & 1, cw = wid >> 1;
    int rbase = blockIdx.x * 64 + rw * 32;
    int cbase = cw * 112;
    int lr = lane & 15, lk = (lane >> 4) * 8;
    f32x4 acc[2][7] = {};
    const float* Ar0 = A + (size_t)(rbase + lr) * FPD + lk;
    const float* Ar1 = A + (size_t)(rbase + 16 + lr) * FPD + lk;
    for (int k0 = 0; k0 < FPD; k0 += 32) {
        half8 a0 = load_a_frag(Ar0 + k0);
        half8 a1 = load_a_frag(Ar1 + k0);
        #pragma unroll
        for (int nt = 0; nt < 7; ++nt) {
            half8 b = *(const half8*)&Wt[(size_t)(cbase + nt * 16 + lr) * FPD + k0 + lk];
            acc[0][nt] = __builtin_amdgcn_mfma_f32_16x16x32_f16(a0, b, acc[0][nt], 0, 0, 0);
            acc[1][nt] = __builtin_amdgcn_mfma_f32_16x16x32_f16(a1, b, acc[1][nt], 0, 0, 0);
        }
    }
    int rj = (lane >> 4) * 4;
    #pragma unroll
    for (int nt = 0; nt < 7; ++nt) {
        int col = cbase + nt * 16 + lr;
        if (col < 200) {
            #pragma unroll
            for (int mt = 0; mt < 2; ++mt)
                #pragma unroll
                for (int j = 0; j < 4; ++j)
                    Z[(size_t)(rbase + mt * 16 + rj + j) * 200 + col] = acc[mt][nt][j];
        }
    }
}

// ---------------- gather 1: p1 = relu(Z1[n] + sum_d Z1[e] + bp1), width 200 ----------------
__global__ __launch_bounds__(256) void k_ga1(
        const float* __restrict__ Z, const int* __restrict__ edges,
        const float* __restrict__ bias, float* __restrict__ out) {
    int bid = blockIdx.x;                      // 2048 = 64 b x 32 tiles, XCD-swizzled
    int x = bid & 7, j = bid >> 3;
    int b = (j >> 5) * 8 + x, tile = j & 31;
    int n0 = tile * 16, tid = threadIdx.x;
    __shared__ int e[16 * DP];
    if (tid < 16 * DP)
        e[tid] = edges[(b * NP + n0 + tid / DP) * DP + tid % DP];
    __syncthreads();
    const float4* Zb = (const float4*)(Z + (size_t)b * NP * 200);
    float4* ob = (float4*)(out + (size_t)b * NP * 200);
    const float4* b4 = (const float4*)bias;
    for (int idx = tid; idx < 16 * 50; idx += 256) {
        int r = idx / 50, c = idx % 50;
        float4 v = Zb[(n0 + r) * 50 + c];
        #pragma unroll
        for (int d = 0; d < DP; ++d) v = f4add(v, Zb[e[r * DP + d] * 50 + c]);
        v = f4add(v, b4[c]);
        ob[(n0 + r) * 50 + c] = make_float4(fmaxf(v.x, 0.f), fmaxf(v.y, 0.f),
                                            fmaxf(v.z, 0.f), fmaxf(v.w, 0.f));
    }
}

// ---------------- MFMA GEMM 2: Z2 = p1 @ Wp2  [32768,200]x[200,100] ----------------
// 4 row-waves; wave-tile 32x112; block-tile 128x112; K padded 200->224 (B zero-pad)
__global__ __launch_bounds__(256) void k_zp2(
        const float* __restrict__ A, const _Float16* __restrict__ Wt,
        float* __restrict__ Z) {
    int tid = threadIdx.x, lane = tid & 63, wid = tid >> 6;
    int rbase = blockIdx.x * 128 + wid * 32;
    int lr = lane & 15, lk = (lane >> 4) * 8;
    f32x4 acc[2][7] = {};
    const float* Ar0 = A + (size_t)(rbase + lr) * 200 + lk;
    const float* Ar1 = A + (size_t)(rbase + 16 + lr) * 200 + lk;
    for (int k0 = 0; k0 < 224; k0 += 32) {       // A overreads past 200 -> x0 via B pad
        half8 a0 = load_a_frag(Ar0 + k0);
        half8 a1 = load_a_frag(Ar1 + k0);
        #pragma unroll
        for (int nt = 0; nt < 7; ++nt) {
            half8 b = *(const half8*)&Wt[(size_t)(nt * 16 + lr) * 224 + k0 + lk];
            acc[0][nt] = __builtin_amdgcn_mfma_f32_16x16x32_f16(a0, b, acc[0][nt], 0, 0, 0);
            acc[1][nt] = __builtin_amdgcn_mfma_f32_16x16x32_f16(a1, b, acc[1][nt], 0, 0, 0);
        }
    }
    int rj = (lane >> 4) * 4;
    #pragma unroll
    for (int nt = 0; nt < 7; ++nt) {
        int col = nt * 16 + lr;
        if (col < 100) {
            #pragma unroll
            for (int mt = 0; mt < 2; ++mt)
                #pragma unroll
                for (int j = 0; j < 4; ++j)
                    Z[(size_t)(rbase + mt * 16 + rj + j) * 100 + col] = acc[mt][nt][j];
        }
    }
}

// ---------------- gather 2: p2 = relu(Z2[n] + sum_d Z2[e] + bp2), width 100 ----------------
__global__ __launch_bounds__(256) void k_ga2(
        const float* __restrict__ Z, const int* __restrict__ edges,
        const float* __restrict__ bias, float* __restrict__ out) {
    int bid = blockIdx.x;
    int x = bid & 7, j = bid >> 3;
    int b = (j >> 5) * 8 + x, tile = j & 31;
    int n0 = tile * 16, tid = threadIdx.x;
    __shared__ int e[16 * DP];
    if (tid < 16 * DP)
        e[tid] = edges[(b * NP + n0 + tid / DP) * DP + tid % DP];
    __syncthreads();
    const float4* Zb = (const float4*)(Z + (size_t)b * NP * 100);
    float4* ob = (float4*)(out + (size_t)b * NP * 100);
    const float4* b4 = (const float4*)bias;
    for (int idx = tid; idx < 16 * 25; idx += 256) {
        int r = idx / 25, c = idx % 25;
        float4 v = Zb[(n0 + r) * 25 + c];
        #pragma unroll
        for (int d = 0; d < DP; ++d) v = f4add(v, Zb[e[r * DP + d] * 25 + c]);
        v = f4add(v, b4[c]);
        ob[(n0 + r) * 25 + c] = make_float4(fmaxf(v.x, 0.f), fmaxf(v.y, 0.f),
                                            fmaxf(v.z, 0.f), fmaxf(v.w, 0.f));
    }
}

// ---------------- protein GraphOutput (MFMA): tanh(p2@Wop+bop) summed over atoms ----------------
// wave-tile 32x128 (8 n-tiles); block 128 rows; K 100->128 pad
__global__ __launch_bounds__(256) void k_pout(
        const float* __restrict__ A, const _Float16* __restrict__ Wt,
        const float* __restrict__ bias, float* __restrict__ fpp) {
    int tid = threadIdx.x, lane = tid & 63, wid = tid >> 6;
    int rbase = blockIdx.x * 128 + wid * 32;
    int lr = lane & 15, lk = (lane >> 4) * 8;
    f32x4 acc[2][8] = {};
    const float* Ar0 = A + (size_t)(rbase + lr) * 100 + lk;
    const float* Ar1 = A + (size_t)(rbase + 16 + lr) * 100 + lk;
    for (int k0 = 0; k0 < 128; k0 += 32) {
        half8 a0 = load_a_frag(Ar0 + k0);
        half8 a1 = load_a_frag(Ar1 + k0);
        #pragma unroll
        for (int nt = 0; nt < 8; ++nt) {
            half8 b = *(const half8*)&Wt[(size_t)(nt * 16 + lr) * 128 + k0 + lk];
            acc[0][nt] = __builtin_amdgcn_mfma_f32_16x16x32_f16(a0, b, acc[0][nt], 0, 0, 0);
            acc[1][nt] = __builtin_amdgcn_mfma_f32_16x16x32_f16(a1, b, acc[1][nt], 0, 0, 0);
        }
    }
    int bmol = blockIdx.x >> 2;                  // 4 blocks (512 rows) per molecule
    #pragma unroll
    for (int nt = 0; nt < 8; ++nt) {
        float bb = bias[nt * 16 + lr];
        float s = 0.f;
        #pragma unroll
        for (int mt = 0; mt < 2; ++mt)
            #pragma unroll
            for (int j = 0; j < 4; ++j)
                s += tanhf(acc[mt][nt][j] + bb);
        s += __shfl_xor(s, 16);
        s += __shfl_xor(s, 32);                  // sum over 32 rows, all lanes hold it
        if (lane < 16) atomicAdd(&fpp[bmol * 128 + nt * 16 + lane], s);
    }
}

// ---------------- molecule kernels (unchanged) ----------------
__global__ void k_bondsum(const float* __restrict__ bonds, float* __restrict__ bond_sum) {
    int idx = blockIdx.x * blockDim.x + threadIdx.x;
    if (idx >= B * NM * FB) return;
    int f = idx % FB, bn = idx / FB;
    float s = 0.f;
    #pragma unroll
    for (int d = 0; d < DM; ++d) s += bonds[(bn * DM + d) * FB + f];
    bond_sum[idx] = s;
}

__global__ __launch_bounds__(128) void k_mol1(
        const float* __restrict__ atoms, const int* __restrict__ edges,
        const float* __restrict__ bond_sum,
        const float* __restrict__ W, const float* __restrict__ bias,
        float* __restrict__ out) {
    int bn = blockIdx.x, b = bn >> 6, tid = threadIdx.x;
    __shared__ float s[43];
    __shared__ int e[DM];
    if (tid < DM) e[tid] = edges[bn * DM + tid];
    __syncthreads();
    if (tid < FA) {
        float v = atoms[bn * FA + tid];
        #pragma unroll
        for (int d = 0; d < DM; ++d) v += atoms[(b * NM + e[d]) * FA + tid];
        s[tid] = v;
    } else if (tid < FA + FB) {
        s[tid] = bond_sum[bn * FB + (tid - FA)];
    }
    __syncthreads();
    float acc = bias[tid];
    for (int k = 0; k < FA + FB; ++k) acc = fmaf(s[k], W[k * 128 + tid], acc);
    out[bn * 128 + tid] = fmaxf(acc, 0.f);
}

__global__ __launch_bounds__(128) void k_mol2(
        const float* __restrict__ a1, const int* __restrict__ edges,
        const float* __restrict__ bond_sum,
        const float* __restrict__ W, const float* __restrict__ bias,
        float* __restrict__ out) {
    int bn = blockIdx.x, b = bn >> 6, tid = threadIdx.x;
    __shared__ float s[134];
    __shared__ int e[DM];
    if (tid < DM) e[tid] = edges[bn * DM + tid];
    __syncthreads();
    float v = a1[bn * 128 + tid];
    #pragma unroll
    for (int d = 0; d < DM; ++d) v += a1[(b * NM + e[d]) * 128 + tid];
    s[tid] = v;
    if (tid < FB) s[128 + tid] = bond_sum[bn * FB + tid];
    __syncthreads();
    float acc = bias[tid];
    for (int k = 0; k < 134; ++k) acc = fmaf(s[k], W[k * 128 + tid], acc);
    out[bn * 128 + tid] = fmaxf(acc, 0.f);
}

__global__ __launch_bounds__(128) void k_molout(
        const float* __restrict__ a2, const float* __restrict__ bond_sum,
        const float* __restrict__ W, const float* __restrict__ bias,
        float* __restrict__ fpm) {
    int b = blockIdx.y, g = blockIdx.x, tid = threadIdx.x;
    int n0 = g * 8;
    __shared__ float s[8 * 134];
    for (int t = tid; t < 8 * 134; t += 128) {
        int r = t / 134, k = t % 134, n = n0 + r;
        s[t] = (k < 128) ? a2[(b * NM + n) * 128 + k]
                         : bond_sum[(b * NM + n) * FB + (k - 128)];
    }
    __syncthreads();
    float sum = 0.f;
    for (int r = 0; r < 8; ++r) {
        float acc = bias[tid];
        for (int k = 0; k < 134; ++k) acc = fmaf(s[r * 134 + k], W[k * 128 + tid], acc);
        sum += tanhf(acc);
    }
    atomicAdd(&fpm[b * 128 + tid], sum);
}

// ---------------- FC stack ----------------
__global__ __launch_bounds__(128) void k_fc(
        const float* __restrict__ fpm, const float* __restrict__ fpp,
        const float* __restrict__ Wf1, const float* __restrict__ bf1,
        const float* __restrict__ Wf2, const float* __restrict__ bf2,
        const float* __restrict__ Wout, const float* __restrict__ bout,
        float* __restrict__ out) {
    int b = blockIdx.x, tid = threadIdx.x;
    __shared__ float fp[256], h1[100], h2[100];
    fp[tid]       = fpm[b * 128 + tid];
    fp[tid + 128] = fpp[b * 128 + tid];
    __syncthreads();
    if (tid < 100) {
        float acc = bf1[tid];
        for (int k = 0; k < 256; ++k) acc = fmaf(fp[k], Wf1[k * 100 + tid], acc);
        h1[tid] = acc;
    }
    __syncthreads();
    if (tid < 100) {
        float acc = bf2[tid];
        for (int k = 0; k < 100; ++k) acc = fmaf(h1[k], Wf2[k * 100 + tid], acc);
        h2[tid] = acc;
    }
    __syncthreads();
    if (tid < 64) {
        float v = h2[tid] * Wout[tid];
        if (tid + 64 < 100) v += h2[tid + 64] * Wout[tid + 64];
        #pragma unroll
        for (int off = 32; off > 0; off >>= 1) v += __shfl_down(v, off);
        if (tid == 0) out[b] = 1.f / (1.f + expf(-(v + bout[0])));
    }
}

extern "C" void kernel_launch(void* const* d_in, const int* in_sizes, int n_in,
                              void* d_out, int out_size, void* d_ws, size_t ws_size,
                              hipStream_t stream) {
    const float* m_atoms = (const float*)d_in[0];
    const float* m_bonds = (const float*)d_in[1];
    const int*   m_edges = (const int*)  d_in[2];
    const float* p_atoms = (const float*)d_in[3];
    const int*   p_edges = (const int*)  d_in[4];
    const float* W1   = (const float*)d_in[5];  const float* b1   = (const float*)d_in[6];
    const float* W2   = (const float*)d_in[7];  const float* b2   = (const float*)d_in[8];
    const float* Wp1  = (const float*)d_in[9];  const float* bp1  = (const float*)d_in[10];
    const float* Wp2  = (const float*)d_in[11]; const float* bp2  = (const float*)d_in[12];
    const float* Wo   = (const float*)d_in[13]; const float* bo   = (const float*)d_in[14];
    const float* Wop  = (const float*)d_in[15]; const float* bop  = (const float*)d_in[16];
    const float* Wf1  = (const float*)d_in[17]; const float* bf1  = (const float*)d_in[18];
    const float* Wf2  = (const float*)d_in[19]; const float* bf2  = (const float*)d_in[20];
    const float* Wout = (const float*)d_in[21]; const float* bout = (const float*)d_in[22];

    float* ws       = (float*)d_ws;
    float* bond_sum = ws + OFF_BOND;
    float* a1       = ws + OFF_A1;
    float* a2       = ws + OFF_A2;
    float* fpm      = ws + OFF_FPM;
    float* fpp      = ws + OFF_FPP;
    float* zbuf     = ws + OFF_Z;   // Z1 (200-wide), then Z2 (100-wide)
    float* pbuf     = ws + OFF_P;   // p1 (200-wide), then p2 (100-wide)
    _Float16* w16   = (_Float16*)(ws + OFF_W16);

    hipMemsetAsync(fpm, 0, (size_t)2 * B * 128 * sizeof(float), stream);
    k_prep<<<dim3((W16_TOT + 255) / 256), 256, 0, stream>>>(Wp1, Wp2, Wop, w16);

    // protein path: MFMA GEMM -> gather -> MFMA GEMM -> gather -> MFMA output
    k_zp1 <<<dim3(B * NP / 64), 256, 0, stream>>>(p_atoms, w16 + W16_WT1, zbuf);
    k_ga1 <<<dim3(B * NP / 16), 256, 0, stream>>>(zbuf, p_edges, bp1, pbuf);
    k_zp2 <<<dim3(B * NP / 128), 256, 0, stream>>>(pbuf, w16 + W16_WT2, zbuf);
    k_ga2 <<<dim3(B * NP / 16), 256, 0, stream>>>(zbuf, p_edges, bp2, pbuf);
    k_pout<<<dim3(B * NP / 128), 256, 0, stream>>>(pbuf, w16 + W16_WTOP, bop, fpp);

    // molecule path
    k_bondsum<<<dim3((B * NM * FB + 255) / 256), 256, 0, stream>>>(m_bonds, bond_sum);
    k_mol1  <<<dim3(B * NM), 128, 0, stream>>>(m_atoms, m_edges, bond_sum, W1, b1, a1);
    k_mol2  <<<dim3(B * NM), 128, 0, stream>>>(a1, m_edges, bond_sum, W2, b2, a2);
    k_molout<<<dim3(NM / 8, B), 128, 0, stream>>>(a2, bond_sum, Wo, bo, fpm);

    k_fc    <<<dim3(B), 128, 0, stream>>>(fpm, fpp, Wf1, bf1, Wf2, bf2, Wout, bout, (float*)d_out);
}

// Round 5
// 272.887 us; speedup vs baseline: 1.9767x; 1.2896x over previous
//
#include <hip/hip_runtime.h>
#include <cmath>

#define B   64
#define NM  64
#define DM  6
#define FA  37
#define FB  6
#define NP  512
#define DP  12
#define FPD 480
#define HM  128
#define HP  128

typedef _Float16 half8 __attribute__((ext_vector_type(8)));
typedef float f32x4 __attribute__((ext_vector_type(4)));

// ---------------- ws layout (floats) ----------------
static const size_t OFF_FPP  = 0;                               // B*128
static const size_t OFF_Z    = OFF_FPP + (size_t)B*128;         // B*NP*200 (Z1, later Z2 [100-wide])
static const size_t OFF_P    = OFF_Z   + (size_t)B*NP*200;      // B*NP*200 (p1, later p2 [100-wide])
static const size_t OFF_W16  = OFF_P   + (size_t)B*NP*200 + 256;  // fp16 weights (+256 slack for A overread)
// fp16 sub-offsets (in _Float16 units, from OFF_W16)
#define W16_WT1   0          // [224][480]  protein Wp1^T
#define W16_WT2   107520     // [112][224]  protein Wp2^T
#define W16_WTOP  132608     // [128][128]  protein Wop^T
#define W16_MW1T  148992     // [128][64]   mol W1^T  (k<43)
#define W16_MW2T  157184     // [128][160]  mol W2^T  (k<134)
#define W16_MWOT  177664     // [128][160]  mol Wo^T  (k<134)
#define W16_TOT   198144
// ws total ~= 13.2M floats = 52.9 MB

__device__ __forceinline__ float4 f4add(float4 a, float4 b) {
    return make_float4(a.x + b.x, a.y + b.y, a.z + b.z, a.w + b.w);
}

__device__ __forceinline__ half8 load_a_frag(const float* p) {
    float4 f0 = *(const float4*)(p);
    float4 f1 = *(const float4*)(p + 4);
    half8 h;
    h[0] = (_Float16)f0.x; h[1] = (_Float16)f0.y; h[2] = (_Float16)f0.z; h[3] = (_Float16)f0.w;
    h[4] = (_Float16)f1.x; h[5] = (_Float16)f1.y; h[6] = (_Float16)f1.z; h[7] = (_Float16)f1.w;
    return h;
}

// ---------------- weight prep: transpose + pad + fp16 (protein + molecule) ----------------
__global__ void k_prep(const float* __restrict__ Wp1, const float* __restrict__ Wp2,
                       const float* __restrict__ Wop,
                       const float* __restrict__ W1,  const float* __restrict__ W2,
                       const float* __restrict__ Wo,  _Float16* __restrict__ w16) {
    int idx = blockIdx.x * 256 + threadIdx.x;
    if (idx < 224 * 480) {                       // Wt1[n][k] = Wp1[k][n], n<200
        int n = idx / 480, k = idx % 480;
        w16[idx] = (n < 200) ? (_Float16)Wp1[k * 200 + n] : (_Float16)0.f;
    } else if (idx < W16_WTOP) {                 // Wt2[n][k] = Wp2[k][n], n<100,k<200
        int r = idx - W16_WT2;
        int n = r / 224, k = r % 224;
        w16[idx] = (n < 100 && k < 200) ? (_Float16)Wp2[k * 100 + n] : (_Float16)0.f;
    } else if (idx < W16_MW1T) {                 // Wtop[n][k] = Wop[k][n], k<100
        int r = idx - W16_WTOP;
        int n = r >> 7, k = r & 127;
        w16[idx] = (k < 100) ? (_Float16)Wop[k * 128 + n] : (_Float16)0.f;
    } else if (idx < W16_MW2T) {                 // MW1t[n][k] = W1[k][n], k<43
        int r = idx - W16_MW1T;
        int n = r >> 6, k = r & 63;
        w16[idx] = (k < 43) ? (_Float16)W1[k * 128 + n] : (_Float16)0.f;
    } else if (idx < W16_MWOT) {                 // MW2t[n][k] = W2[k][n], k<134
        int r = idx - W16_MW2T;
        int n = r / 160, k = r % 160;
        w16[idx] = (k < 134) ? (_Float16)W2[k * 128 + n] : (_Float16)0.f;
    } else if (idx < W16_TOT) {                  // MWot[n][k] = Wo[k][n], k<134
        int r = idx - W16_MWOT;
        int n = r / 160, k = r % 160;
        w16[idx] = (k < 134) ? (_Float16)Wo[k * 128 + n] : (_Float16)0.f;
    }
}

// ---------------- MFMA GEMM 1: Z1 = p_atoms @ Wp1  [32768,480]x[480,200] ----------------
__global__ __launch_bounds__(256) void k_zp1(
        const float* __restrict__ A, const _Float16* __restrict__ Wt,
        float* __restrict__ Z) {
    int tid = threadIdx.x, lane = tid & 63, wid = tid >> 6;
    int rw = wid & 1, cw = wid >> 1;
    int rbase = blockIdx.x * 64 + rw * 32;
    int cbase = cw * 112;
    int lr = lane & 15, lk = (lane >> 4) * 8;
    f32x4 acc[2][7] = {};
    const float* Ar0 = A + (size_t)(rbase + lr) * FPD + lk;
    const float* Ar1 = A + (size_t)(rbase + 16 + lr) * FPD + lk;
    for (int k0 = 0; k0 < FPD; k0 += 32) {
        half8 a0 = load_a_frag(Ar0 + k0);
        half8 a1 = load_a_frag(Ar1 + k0);
        #pragma unroll
        for (int nt = 0; nt < 7; ++nt) {
            half8 b = *(const half8*)&Wt[(size_t)(cbase + nt * 16 + lr) * FPD + k0 + lk];
            acc[0][nt] = __builtin_amdgcn_mfma_f32_16x16x32_f16(a0, b, acc[0][nt], 0, 0, 0);
            acc[1][nt] = __builtin_amdgcn_mfma_f32_16x16x32_f16(a1, b, acc[1][nt], 0, 0, 0);
        }
    }
    int rj = (lane >> 4) * 4;
    #pragma unroll
    for (int nt = 0; nt < 7; ++nt) {
        int col = cbase + nt * 16 + lr;
        if (col < 200) {
            #pragma unroll
            for (int mt = 0; mt < 2; ++mt)
                #pragma unroll
                for (int j = 0; j < 4; ++j)
                    Z[(size_t)(rbase + mt * 16 + rj + j) * 200 + col] = acc[mt][nt][j];
        }
    }
}

// ---------------- gather 1: p1 = relu(Z1[n] + sum_d Z1[e] + bp1), width 200 ----------------
__global__ __launch_bounds__(256) void k_ga1(
        const float* __restrict__ Z, const int* __restrict__ edges,
        const float* __restrict__ bias, float* __restrict__ out) {
    int bid = blockIdx.x;                      // 2048 = 64 b x 32 tiles, XCD-swizzled
    int x = bid & 7, j = bid >> 3;
    int b = (j >> 5) * 8 + x, tile = j & 31;
    int n0 = tile * 16, tid = threadIdx.x;
    __shared__ int e[16 * DP];
    if (tid < 16 * DP)
        e[tid] = edges[(b * NP + n0 + tid / DP) * DP + tid % DP];
    __syncthreads();
    const float4* Zb = (const float4*)(Z + (size_t)b * NP * 200);
    float4* ob = (float4*)(out + (size_t)b * NP * 200);
    const float4* b4 = (const float4*)bias;
    for (int idx = tid; idx < 16 * 50; idx += 256) {
        int r = idx / 50, c = idx % 50;
        float4 v = Zb[(n0 + r) * 50 + c];
        #pragma unroll
        for (int d = 0; d < DP; ++d) v = f4add(v, Zb[e[r * DP + d] * 50 + c]);
        v = f4add(v, b4[c]);
        ob[(n0 + r) * 50 + c] = make_float4(fmaxf(v.x, 0.f), fmaxf(v.y, 0.f),
                                            fmaxf(v.z, 0.f), fmaxf(v.w, 0.f));
    }
}

// ---------------- MFMA GEMM 2: Z2 = p1 @ Wp2  [32768,200]x[200,100] ----------------
__global__ __launch_bounds__(256) void k_zp2(
        const float* __restrict__ A, const _Float16* __restrict__ Wt,
        float* __restrict__ Z) {
    int tid = threadIdx.x, lane = tid & 63, wid = tid >> 6;
    int rbase = blockIdx.x * 128 + wid * 32;
    int lr = lane & 15, lk = (lane >> 4) * 8;
    f32x4 acc[2][7] = {};
    const float* Ar0 = A + (size_t)(rbase + lr) * 200 + lk;
    const float* Ar1 = A + (size_t)(rbase + 16 + lr) * 200 + lk;
    for (int k0 = 0; k0 < 224; k0 += 32) {       // A overreads past 200 -> x0 via B pad
        half8 a0 = load_a_frag(Ar0 + k0);
        half8 a1 = load_a_frag(Ar1 + k0);
        #pragma unroll
        for (int nt = 0; nt < 7; ++nt) {
            half8 b = *(const half8*)&Wt[(size_t)(nt * 16 + lr) * 224 + k0 + lk];
            acc[0][nt] = __builtin_amdgcn_mfma_f32_16x16x32_f16(a0, b, acc[0][nt], 0, 0, 0);
            acc[1][nt] = __builtin_amdgcn_mfma_f32_16x16x32_f16(a1, b, acc[1][nt], 0, 0, 0);
        }
    }
    int rj = (lane >> 4) * 4;
    #pragma unroll
    for (int nt = 0; nt < 7; ++nt) {
        int col = nt * 16 + lr;
        if (col < 100) {
            #pragma unroll
            for (int mt = 0; mt < 2; ++mt)
                #pragma unroll
                for (int j = 0; j < 4; ++j)
                    Z[(size_t)(rbase + mt * 16 + rj + j) * 100 + col] = acc[mt][nt][j];
        }
    }
}

// ---------------- gather 2: p2 = relu(Z2[n] + sum_d Z2[e] + bp2), width 100 ----------------
__global__ __launch_bounds__(256) void k_ga2(
        const float* __restrict__ Z, const int* __restrict__ edges,
        const float* __restrict__ bias, float* __restrict__ out) {
    int bid = blockIdx.x;
    int x = bid & 7, j = bid >> 3;
    int b = (j >> 5) * 8 + x, tile = j & 31;
    int n0 = tile * 16, tid = threadIdx.x;
    __shared__ int e[16 * DP];
    if (tid < 16 * DP)
        e[tid] = edges[(b * NP + n0 + tid / DP) * DP + tid % DP];
    __syncthreads();
    const float4* Zb = (const float4*)(Z + (size_t)b * NP * 100);
    float4* ob = (float4*)(out + (size_t)b * NP * 100);
    const float4* b4 = (const float4*)bias;
    for (int idx = tid; idx < 16 * 25; idx += 256) {
        int r = idx / 25, c = idx % 25;
        float4 v = Zb[(n0 + r) * 25 + c];
        #pragma unroll
        for (int d = 0; d < DP; ++d) v = f4add(v, Zb[e[r * DP + d] * 25 + c]);
        v = f4add(v, b4[c]);
        ob[(n0 + r) * 25 + c] = make_float4(fmaxf(v.x, 0.f), fmaxf(v.y, 0.f),
                                            fmaxf(v.z, 0.f), fmaxf(v.w, 0.f));
    }
}

// ---------------- protein GraphOutput (MFMA): tanh(p2@Wop+bop) summed over atoms ----------------
__global__ __launch_bounds__(256) void k_pout(
        const float* __restrict__ A, const _Float16* __restrict__ Wt,
        const float* __restrict__ bias, float* __restrict__ fpp) {
    int tid = threadIdx.x, lane = tid & 63, wid = tid >> 6;
    int rbase = blockIdx.x * 128 + wid * 32;
    int lr = lane & 15, lk = (lane >> 4) * 8;
    f32x4 acc[2][8] = {};
    const float* Ar0 = A + (size_t)(rbase + lr) * 100 + lk;
    const float* Ar1 = A + (size_t)(rbase + 16 + lr) * 100 + lk;
    for (int k0 = 0; k0 < 128; k0 += 32) {
        half8 a0 = load_a_frag(Ar0 + k0);
        half8 a1 = load_a_frag(Ar1 + k0);
        #pragma unroll
        for (int nt = 0; nt < 8; ++nt) {
            half8 b = *(const half8*)&Wt[(size_t)(nt * 16 + lr) * 128 + k0 + lk];
            acc[0][nt] = __builtin_amdgcn_mfma_f32_16x16x32_f16(a0, b, acc[0][nt], 0, 0, 0);
            acc[1][nt] = __builtin_amdgcn_mfma_f32_16x16x32_f16(a1, b, acc[1][nt], 0, 0, 0);
        }
    }
    int bmol = blockIdx.x >> 2;                  // 4 blocks (512 rows) per molecule
    #pragma unroll
    for (int nt = 0; nt < 8; ++nt) {
        float bb = bias[nt * 16 + lr];
        float s = 0.f;
        #pragma unroll
        for (int mt = 0; mt < 2; ++mt)
            #pragma unroll
            for (int j = 0; j < 4; ++j)
                s += tanhf(acc[mt][nt][j] + bb);
        s += __shfl_xor(s, 16);
        s += __shfl_xor(s, 32);                  // sum over 32 rows, all lanes hold it
        if (lane < 16) atomicAdd(&fpp[bmol * 128 + nt * 16 + lane], s);
    }
}

// ---------------- FUSED molecule path + FC: one block per molecule ----------------
// LDS carve (floats): [0..4352) region1: atoms[64][40] then a1 fp16 [64][136]
//                     [4352..9728) region2: S1 fp16 [64][72] then S23 fp16 [64][168]
//                     [9728..10112) bond[64*6]; [10112..10496) edges (int) [64*6]
//                     [10496..11008) red[4][128]; [11008..11464) fc: fp[256] h1[100] h2[100]
#define P_ATOM 40
#define P_S1   72
#define P_A    136
#define P_S23  168
__global__ __launch_bounds__(512) void k_mol(
        const float* __restrict__ m_atoms, const float* __restrict__ m_bonds,
        const int* __restrict__ m_edges,
        const _Float16* __restrict__ W1t, const _Float16* __restrict__ W2t,
        const _Float16* __restrict__ Wot,
        const float* __restrict__ b1, const float* __restrict__ b2,
        const float* __restrict__ bo,
        const float* __restrict__ fpp,
        const float* __restrict__ Wf1, const float* __restrict__ bf1,
        const float* __restrict__ Wf2, const float* __restrict__ bf2,
        const float* __restrict__ Wout, const float* __restrict__ bout,
        float* __restrict__ out) {
    int b = blockIdx.x, tid = threadIdx.x;
    __shared__ __align__(16) float smem[11464];
    float*     atoms_sh = smem;                        // [64][40] fp32
    _Float16*  a1  = (_Float16*)smem;                  // [64][136] fp16 (after atoms dead)
    _Float16*  S1  = (_Float16*)(smem + 4352);         // [64][72] fp16
    _Float16*  S23 = (_Float16*)(smem + 4352);         // [64][168] fp16 (after S1 dead)
    float*     bond  = smem + 9728;                    // [64][6]
    int*       edg   = (int*)(smem + 10112);           // [64][6]
    float*     red   = smem + 10496;                   // [4][128]
    float*     fcb   = smem + 11008;                   // fp[256] h1[100] h2[100]

    // ---- stage atoms / edges / bond-sum ----
    const float* ga = m_atoms + (size_t)b * NM * FA;
    for (int i = tid; i < NM * FA; i += 512)
        atoms_sh[(i / FA) * P_ATOM + (i % FA)] = ga[i];
    if (tid < NM * DM) edg[tid] = m_edges[b * NM * DM + tid];
    if (tid < NM * FB) {
        int r = tid / FB, j = tid % FB;
        float s = 0.f;
        #pragma unroll
        for (int d = 0; d < DM; ++d) s += m_bonds[((size_t)(b * NM + r) * DM + d) * FB + j];
        bond[tid] = s;
    }
    __syncthreads();

    // ---- S1 = [atoms + nbr_sum | bond | 0pad] fp16, K 64 ----
    for (int i = tid; i < 64 * 64; i += 512) {
        int r = i >> 6, k = i & 63;
        float v = 0.f;
        if (k < FA) {
            v = atoms_sh[r * P_ATOM + k];
            #pragma unroll
            for (int d = 0; d < DM; ++d) v += atoms_sh[edg[r * DM + d] * P_ATOM + k];
        } else if (k < FA + FB) {
            v = bond[r * FB + (k - FA)];
        }
        S1[r * P_S1 + k] = (_Float16)v;
    }
    __syncthreads();

    // ---- wave geometry: 8 waves = 4 row x 2 col; wave-tile 16 rows x 64 cols ----
    int lane = tid & 63, wid = tid >> 6;
    int rw = wid & 3, cw = wid >> 2;
    int rbase = rw * 16, cbase = cw * 64;
    int lr = lane & 15, lkb = (lane >> 4) * 8, rj = (lane >> 4) * 4;

    // ---- L1: a1 = relu(S1 @ W1t + b1) ----
    {
        f32x4 acc[4] = {};
        for (int k0 = 0; k0 < 64; k0 += 32) {
            half8 a = *(const half8*)&S1[(rbase + lr) * P_S1 + k0 + lkb];
            #pragma unroll
            for (int nt = 0; nt < 4; ++nt) {
                half8 bf = *(const half8*)&W1t[(cbase + nt * 16 + lr) * 64 + k0 + lkb];
                acc[nt] = __builtin_amdgcn_mfma_f32_16x16x32_f16(a, bf, acc[nt], 0, 0, 0);
            }
        }
        #pragma unroll
        for (int nt = 0; nt < 4; ++nt) {
            int col = cbase + nt * 16 + lr;
            float bb = b1[col];
            #pragma unroll
            for (int j = 0; j < 4; ++j)
                a1[(rbase + rj + j) * P_A + col] = (_Float16)fmaxf(acc[nt][j] + bb, 0.f);
        }
    }
    __syncthreads();

    // ---- S2 = [a1 + nbr_sum(a1) | bond | 0pad] fp16, K 160 (overwrites S1) ----
    for (int i = tid; i < 64 * 160; i += 512) {
        int r = i / 160, k = i % 160;
        float v = 0.f;
        if (k < 128) {
            v = (float)a1[r * P_A + k];
            #pragma unroll
            for (int d = 0; d < DM; ++d) v += (float)a1[edg[r * DM + d] * P_A + k];
        } else if (k < 134) {
            v = bond[r * FB + (k - 128)];
        }
        S23[r * P_S23 + k] = (_Float16)v;
    }
    __syncthreads();

    // ---- L2: a2 = relu(S2 @ W2t + b2) ----
    f32x4 acc2[4] = {};
    for (int k0 = 0; k0 < 160; k0 += 32) {
        half8 a = *(const half8*)&S23[(rbase + lr) * P_S23 + k0 + lkb];
        #pragma unroll
        for (int nt = 0; nt < 4; ++nt) {
            half8 bf = *(const half8*)&W2t[(cbase + nt * 16 + lr) * 160 + k0 + lkb];
            acc2[nt] = __builtin_amdgcn_mfma_f32_16x16x32_f16(a, bf, acc2[nt], 0, 0, 0);
        }
    }
    __syncthreads();   // everyone done reading S2 before overwrite with S3

    // ---- S3 = [a2 | bond | 0pad] (in place over S2) ----
    #pragma unroll
    for (int nt = 0; nt < 4; ++nt) {
        int col = cbase + nt * 16 + lr;
        float bb = b2[col];
        #pragma unroll
        for (int j = 0; j < 4; ++j)
            S23[(rbase + rj + j) * P_S23 + col] = (_Float16)fmaxf(acc2[nt][j] + bb, 0.f);
    }
    for (int i = tid; i < 64 * 32; i += 512) {
        int r = i >> 5, k = 128 + (i & 31);
        S23[r * P_S23 + k] = (k < 134) ? (_Float16)bond[r * FB + (k - 128)] : (_Float16)0.f;
    }
    __syncthreads();

    // ---- L3: fpm = sum_rows tanh(S3 @ Wot + bo) ----
    {
        f32x4 acc3[4] = {};
        for (int k0 = 0; k0 < 160; k0 += 32) {
            half8 a = *(const half8*)&S23[(rbase + lr) * P_S23 + k0 + lkb];
            #pragma unroll
            for (int nt = 0; nt < 4; ++nt) {
                half8 bf = *(const half8*)&Wot[(cbase + nt * 16 + lr) * 160 + k0 + lkb];
                acc3[nt] = __builtin_amdgcn_mfma_f32_16x16x32_f16(a, bf, acc3[nt], 0, 0, 0);
            }
        }
        #pragma unroll
        for (int nt = 0; nt < 4; ++nt) {
            int col = cbase + nt * 16 + lr;
            float bb = bo[col];
            float s = 0.f;
            #pragma unroll
            for (int j = 0; j < 4; ++j) s += tanhf(acc3[nt][j] + bb);
            s += __shfl_xor(s, 16);
            s += __shfl_xor(s, 32);             // 16-row colsum
            if (lane < 16) red[rw * 128 + col] = s;
        }
    }
    __syncthreads();

    // ---- FC: fp=[fpm|fpp] -> 100 -> 100 -> 1 -> sigmoid ----
    if (tid < 128)       fcb[tid] = red[tid] + red[128 + tid] + red[256 + tid] + red[384 + tid];
    else if (tid < 256)  fcb[tid] = fpp[b * 128 + (tid - 128)];
    __syncthreads();
    if (tid < 100) {
        float acc = bf1[tid];
        for (int k = 0; k < 256; ++k) acc = fmaf(fcb[k], Wf1[k * 100 + tid], acc);
        fcb[256 + tid] = acc;
    }
    __syncthreads();
    if (tid < 100) {
        float acc = bf2[tid];
        for (int k = 0; k < 100; ++k) acc = fmaf(fcb[256 + k], Wf2[k * 100 + tid], acc);
        fcb[356 + tid] = acc;
    }
    __syncthreads();
    if (tid < 64) {
        float v = fcb[356 + tid] * Wout[tid];
        if (tid + 64 < 100) v += fcb[356 + tid + 64] * Wout[tid + 64];
        #pragma unroll
        for (int off = 32; off > 0; off >>= 1) v += __shfl_down(v, off);
        if (tid == 0) out[b] = 1.f / (1.f + expf(-(v + bout[0])));
    }
}

extern "C" void kernel_launch(void* const* d_in, const int* in_sizes, int n_in,
                              void* d_out, int out_size, void* d_ws, size_t ws_size,
                              hipStream_t stream) {
    const float* m_atoms = (const float*)d_in[0];
    const float* m_bonds = (const float*)d_in[1];
    const int*   m_edges = (const int*)  d_in[2];
    const float* p_atoms = (const float*)d_in[3];
    const int*   p_edges = (const int*)  d_in[4];
    const float* W1   = (const float*)d_in[5];  const float* b1   = (const float*)d_in[6];
    const float* W2   = (const float*)d_in[7];  const float* b2   = (const float*)d_in[8];
    const float* Wp1  = (const float*)d_in[9];  const float* bp1  = (const float*)d_in[10];
    const float* Wp2  = (const float*)d_in[11]; const float* bp2  = (const float*)d_in[12];
    const float* Wo   = (const float*)d_in[13]; const float* bo   = (const float*)d_in[14];
    const float* Wop  = (const float*)d_in[15]; const float* bop  = (const float*)d_in[16];
    const float* Wf1  = (const float*)d_in[17]; const float* bf1  = (const float*)d_in[18];
    const float* Wf2  = (const float*)d_in[19]; const float* bf2  = (const float*)d_in[20];
    const float* Wout = (const float*)d_in[21]; const float* bout = (const float*)d_in[22];

    float* ws   = (float*)d_ws;
    float* fpp  = ws + OFF_FPP;
    float* zbuf = ws + OFF_Z;   // Z1 (200-wide), then Z2 (100-wide)
    float* pbuf = ws + OFF_P;   // p1 (200-wide), then p2 (100-wide)
    _Float16* w16 = (_Float16*)(ws + OFF_W16);

    hipMemsetAsync(fpp, 0, (size_t)B * 128 * sizeof(float), stream);
    k_prep<<<dim3((W16_TOT + 255) / 256), 256, 0, stream>>>(Wp1, Wp2, Wop, W1, W2, Wo, w16);

    // protein path: MFMA GEMM -> gather -> MFMA GEMM -> gather -> MFMA output
    k_zp1 <<<dim3(B * NP / 64), 256, 0, stream>>>(p_atoms, w16 + W16_WT1, zbuf);
    k_ga1 <<<dim3(B * NP / 16), 256, 0, stream>>>(zbuf, p_edges, bp1, pbuf);
    k_zp2 <<<dim3(B * NP / 128), 256, 0, stream>>>(pbuf, w16 + W16_WT2, zbuf);
    k_ga2 <<<dim3(B * NP / 16), 256, 0, stream>>>(zbuf, p_edges, bp2, pbuf);
    k_pout<<<dim3(B * NP / 128), 256, 0, stream>>>(pbuf, w16 + W16_WTOP, bop, fpp);

    // fused molecule path + FC (reads fpp, stream-ordered after k_pout)
    k_mol <<<dim3(B), 512, 0, stream>>>(m_atoms, m_bonds, m_edges,
                                        w16 + W16_MW1T, w16 + W16_MW2T, w16 + W16_MWOT,
                                        b1, b2, bo, fpp,
                                        Wf1, bf1, Wf2, bf2, Wout, bout, (float*)d_out);
}

// Round 6
// 260.720 us; speedup vs baseline: 2.0689x; 1.0467x over previous
//
#include <hip/hip_runtime.h>
#include <cmath>

#define B   64
#define NM  64
#define DM  6
#define FA  37
#define FB  6
#define NP  512
#define DP  12
#define FPD 480
#define HM  128
#define HP  128

typedef _Float16 half8 __attribute__((ext_vector_type(8)));
typedef float f32x4 __attribute__((ext_vector_type(4)));

// ---------------- ws layout ----------------
// floats:
static const size_t OFF_FPP = 0;                                 // B*128
static const size_t OFF_Z1  = OFF_FPP + (size_t)B*128;           // fp16 [32768][224] -> 3,670,016 floats
static const size_t OFF_Z2  = OFF_Z1  + (size_t)32768*224/2;     // fp16 [32768][128] -> 2,097,152 floats
static const size_t OFF_W16 = OFF_Z2  + (size_t)32768*128/2;     // fp16 weights
// fp16 sub-offsets (in _Float16 units, from OFF_W16)
#define W16_WT1   0          // [224][480]  protein Wp1^T (n-pad 224)
#define W16_WT2   107520     // [128][224]  protein Wp2^T (n-pad 128, k-pad 224)
#define W16_WTOP  136192     // [128][128]  protein Wop^T (k-pad 128)
#define W16_MW1T  152576     // [128][64]   mol W1^T  (k<43)
#define W16_MW2T  160768     // [128][160]  mol W2^T  (k<134)
#define W16_MWOT  181248     // [128][160]  mol Wo^T  (k<134)
#define W16_BP1   201728     // [224] bp1 fp16 pad0
#define W16_BP2   201952     // [128] bp2 fp16 pad0
#define W16_TOT   202080
// ws total ~= 5.88M floats = 23.5 MB

__device__ __forceinline__ half8 load_a_frag(const float* p) {
    float4 f0 = *(const float4*)(p);
    float4 f1 = *(const float4*)(p + 4);
    half8 h;
    h[0] = (_Float16)f0.x; h[1] = (_Float16)f0.y; h[2] = (_Float16)f0.z; h[3] = (_Float16)f0.w;
    h[4] = (_Float16)f1.x; h[5] = (_Float16)f1.y; h[6] = (_Float16)f1.z; h[7] = (_Float16)f1.w;
    return h;
}

// ---------------- weight prep: transpose + pad + fp16 ----------------
__global__ void k_prep(const float* __restrict__ Wp1, const float* __restrict__ Wp2,
                       const float* __restrict__ Wop,
                       const float* __restrict__ W1,  const float* __restrict__ W2,
                       const float* __restrict__ Wo,
                       const float* __restrict__ bp1, const float* __restrict__ bp2,
                       _Float16* __restrict__ w16) {
    int idx = blockIdx.x * 256 + threadIdx.x;
    if (idx < W16_WT2) {                         // Wt1[n][k] = Wp1[k][n], n<200
        int n = idx / 480, k = idx % 480;
        w16[idx] = (n < 200) ? (_Float16)Wp1[k * 200 + n] : (_Float16)0.f;
    } else if (idx < W16_WTOP) {                 // Wt2[n][k] = Wp2[k][n], n<100,k<200
        int r = idx - W16_WT2;
        int n = r / 224, k = r % 224;
        w16[idx] = (n < 100 && k < 200) ? (_Float16)Wp2[k * 100 + n] : (_Float16)0.f;
    } else if (idx < W16_MW1T) {                 // Wtop[n][k] = Wop[k][n], k<100
        int r = idx - W16_WTOP;
        int n = r >> 7, k = r & 127;
        w16[idx] = (k < 100) ? (_Float16)Wop[k * 128 + n] : (_Float16)0.f;
    } else if (idx < W16_MW2T) {                 // MW1t[n][k] = W1[k][n], k<43
        int r = idx - W16_MW1T;
        int n = r >> 6, k = r & 63;
        w16[idx] = (k < 43) ? (_Float16)W1[k * 128 + n] : (_Float16)0.f;
    } else if (idx < W16_MWOT) {                 // MW2t[n][k] = W2[k][n], k<134
        int r = idx - W16_MW2T;
        int n = r / 160, k = r % 160;
        w16[idx] = (k < 134) ? (_Float16)W2[k * 128 + n] : (_Float16)0.f;
    } else if (idx < W16_BP1) {                  // MWot[n][k] = Wo[k][n], k<134
        int r = idx - W16_MWOT;
        int n = r / 160, k = r % 160;
        w16[idx] = (k < 134) ? (_Float16)Wo[k * 128 + n] : (_Float16)0.f;
    } else if (idx < W16_BP2) {
        int k = idx - W16_BP1;
        w16[idx] = (k < 200) ? (_Float16)bp1[k] : (_Float16)0.f;
    } else if (idx < W16_TOT) {
        int k = idx - W16_BP2;
        w16[idx] = (k < 100) ? (_Float16)bp2[k] : (_Float16)0.f;
    }
}

// ---------------- MFMA GEMM 1: Z1(fp16) = p_atoms @ Wp1  [32768,480]x[480,224pad] ----
// 4 waves = 2 row x 2 col; wave-tile 16x112; block 32 rows x 224 cols; grid 1024
__global__ __launch_bounds__(256) void k_zp1(
        const float* __restrict__ A, const _Float16* __restrict__ Wt,
        _Float16* __restrict__ Z) {
    int tid = threadIdx.x, lane = tid & 63, wid = tid >> 6;
    int rw = wid & 1, cw = wid >> 1;
    int rbase = blockIdx.x * 32 + rw * 16;
    int cbase = cw * 112;
    int lr = lane & 15, q = lane >> 4, lkb = q * 8;
    f32x4 acc[7] = {};
    const float* Ar = A + (size_t)(rbase + lr) * FPD + lkb;
    for (int k0 = 0; k0 < FPD; k0 += 32) {
        half8 a = load_a_frag(Ar + k0);
        #pragma unroll
        for (int nt = 0; nt < 7; ++nt) {
            half8 b = *(const half8*)&Wt[(size_t)(cbase + nt * 16 + lr) * FPD + k0 + lkb];
            acc[nt] = __builtin_amdgcn_mfma_f32_16x16x32_f16(a, b, acc[nt], 0, 0, 0);
        }
    }
    int rj = q * 4;
    #pragma unroll
    for (int nt = 0; nt < 7; ++nt) {
        int col = cbase + nt * 16 + lr;     // pad cols [200,224) hold 0 via Wt pad
        #pragma unroll
        for (int j = 0; j < 4; ++j)
            Z[(size_t)(rbase + rj + j) * 224 + col] = (_Float16)acc[nt][j];
    }
}

// ---------------- fused gather+GEMM 2: Z2(fp16) = relu(gather(Z1)+bp1) @ Wp2 ----------
// A-row computed on the fly; wave-tile 16x112; block 64 rows; grid 512, XCD-chunked
__global__ __launch_bounds__(256) void k_zp2f(
        const _Float16* __restrict__ Z1, const int* __restrict__ edges,
        const _Float16* __restrict__ bp1h, const _Float16* __restrict__ Wt,
        _Float16* __restrict__ Z2) {
    int bid = blockIdx.x;
    int t = (bid & 7) * 64 + (bid >> 3);         // molecules chunked per XCD
    int tid = threadIdx.x, lane = tid & 63, wid = tid >> 6;
    int lr = lane & 15, q = lane >> 4, lkb = q * 8;
    int rbase = t * 64 + wid * 16;
    int gr = rbase + lr;                          // this lane's A row (global)
    int mb = gr >> 9, lrow = gr & 511;
    const int* ep = edges + (size_t)gr * DP;
    const _Float16* zb = Z1 + ((size_t)mb << 9) * 224;
    const _Float16* src[13];
    src[0] = zb + (size_t)lrow * 224;
    #pragma unroll
    for (int d = 0; d < 12; ++d) src[d + 1] = zb + (size_t)ep[d] * 224;

    f32x4 acc[7] = {};
    for (int k0 = 0; k0 < 224; k0 += 32) {
        int ko = k0 + lkb;
        half8 s = *(const half8*)(src[0] + ko);
        #pragma unroll
        for (int d = 1; d < 13; ++d) s = s + *(const half8*)(src[d] + ko);
        s = s + *(const half8*)(bp1h + ko);
        #pragma unroll
        for (int j = 0; j < 8; ++j) if (s[j] < (_Float16)0.f) s[j] = (_Float16)0.f;
        #pragma unroll
        for (int nt = 0; nt < 7; ++nt) {
            half8 b = *(const half8*)&Wt[(size_t)(nt * 16 + lr) * 224 + ko];
            acc[nt] = __builtin_amdgcn_mfma_f32_16x16x32_f16(s, b, acc[nt], 0, 0, 0);
        }
    }
    int rj = q * 4;
    #pragma unroll
    for (int nt = 0; nt < 7; ++nt) {
        int col = nt * 16 + lr;             // cols [112,128) unwritten: poison is finite,
        #pragma unroll                      // killed by relu + zero Wtop rows downstream
        for (int j = 0; j < 4; ++j)
            Z2[(size_t)(rbase + rj + j) * 128 + col] = (_Float16)acc[nt][j];
    }
}

// ---------------- fused gather+GraphOutput: fpp += colsum tanh(relu(gather(Z2)+bp2)@Wop+bop)
// wave-tile 16x128; block 64 rows; grid 512, XCD-chunked
__global__ __launch_bounds__(256) void k_pof(
        const _Float16* __restrict__ Z2, const int* __restrict__ edges,
        const _Float16* __restrict__ bp2h, const _Float16* __restrict__ Wt,
        const float* __restrict__ bop, float* __restrict__ fpp) {
    int bid = blockIdx.x;
    int t = (bid & 7) * 64 + (bid >> 3);
    int tid = threadIdx.x, lane = tid & 63, wid = tid >> 6;
    int lr = lane & 15, q = lane >> 4, lkb = q * 8;
    int rbase = t * 64 + wid * 16;
    int gr = rbase + lr;
    int mb = gr >> 9, lrow = gr & 511;
    const int* ep = edges + (size_t)gr * DP;
    const _Float16* zb = Z2 + ((size_t)mb << 9) * 128;
    const _Float16* src[13];
    src[0] = zb + (size_t)lrow * 128;
    #pragma unroll
    for (int d = 0; d < 12; ++d) src[d + 1] = zb + (size_t)ep[d] * 128;

    f32x4 acc[8] = {};
    for (int k0 = 0; k0 < 128; k0 += 32) {
        int ko = k0 + lkb;
        half8 s = *(const half8*)(src[0] + ko);
        #pragma unroll
        for (int d = 1; d < 13; ++d) s = s + *(const half8*)(src[d] + ko);
        s = s + *(const half8*)(bp2h + ko);
        #pragma unroll
        for (int j = 0; j < 8; ++j) if (s[j] < (_Float16)0.f) s[j] = (_Float16)0.f;
        #pragma unroll
        for (int nt = 0; nt < 8; ++nt) {
            half8 b = *(const half8*)&Wt[(size_t)(nt * 16 + lr) * 128 + ko];
            acc[nt] = __builtin_amdgcn_mfma_f32_16x16x32_f16(s, b, acc[nt], 0, 0, 0);
        }
    }
    #pragma unroll
    for (int nt = 0; nt < 8; ++nt) {
        int col = nt * 16 + lr;
        float bb = bop[col];
        float s = 0.f;
        #pragma unroll
        for (int j = 0; j < 4; ++j) s += tanhf(acc[nt][j] + bb);
        s += __shfl_xor(s, 16);
        s += __shfl_xor(s, 32);              // sum over the wave's 16 rows
        if (lane < 16) atomicAdd(&fpp[mb * 128 + col], s);
    }
}

// ---------------- FUSED molecule path + FC: one block per molecule ----------------
#define P_ATOM 40
#define P_S1   72
#define P_A    136
#define P_S23  168
__global__ __launch_bounds__(512) void k_mol(
        const float* __restrict__ m_atoms, const float* __restrict__ m_bonds,
        const int* __restrict__ m_edges,
        const _Float16* __restrict__ W1t, const _Float16* __restrict__ W2t,
        const _Float16* __restrict__ Wot,
        const float* __restrict__ b1, const float* __restrict__ b2,
        const float* __restrict__ bo,
        const float* __restrict__ fpp,
        const float* __restrict__ Wf1, const float* __restrict__ bf1,
        const float* __restrict__ Wf2, const float* __restrict__ bf2,
        const float* __restrict__ Wout, const float* __restrict__ bout,
        float* __restrict__ out) {
    int b = blockIdx.x, tid = threadIdx.x;
    __shared__ __align__(16) float smem[11464];
    float*     atoms_sh = smem;                        // [64][40] fp32
    _Float16*  a1  = (_Float16*)smem;                  // [64][136] fp16 (after atoms dead)
    _Float16*  S1  = (_Float16*)(smem + 4352);         // [64][72] fp16
    _Float16*  S23 = (_Float16*)(smem + 4352);         // [64][168] fp16 (after S1 dead)
    float*     bond  = smem + 9728;                    // [64][6]
    int*       edg   = (int*)(smem + 10112);           // [64][6]
    float*     red   = smem + 10496;                   // [4][128]
    float*     fcb   = smem + 11008;                   // fp[256] h1[100] h2[100]

    const float* ga = m_atoms + (size_t)b * NM * FA;
    for (int i = tid; i < NM * FA; i += 512)
        atoms_sh[(i / FA) * P_ATOM + (i % FA)] = ga[i];
    if (tid < NM * DM) edg[tid] = m_edges[b * NM * DM + tid];
    if (tid < NM * FB) {
        int r = tid / FB, j = tid % FB;
        float s = 0.f;
        #pragma unroll
        for (int d = 0; d < DM; ++d) s += m_bonds[((size_t)(b * NM + r) * DM + d) * FB + j];
        bond[tid] = s;
    }
    __syncthreads();

    for (int i = tid; i < 64 * 64; i += 512) {
        int r = i >> 6, k = i & 63;
        float v = 0.f;
        if (k < FA) {
            v = atoms_sh[r * P_ATOM + k];
            #pragma unroll
            for (int d = 0; d < DM; ++d) v += atoms_sh[edg[r * DM + d] * P_ATOM + k];
        } else if (k < FA + FB) {
            v = bond[r * FB + (k - FA)];
        }
        S1[r * P_S1 + k] = (_Float16)v;
    }
    __syncthreads();

    int lane = tid & 63, wid = tid >> 6;
    int rw = wid & 3, cw = wid >> 2;
    int rbase = rw * 16, cbase = cw * 64;
    int lr = lane & 15, lkb = (lane >> 4) * 8, rj = (lane >> 4) * 4;

    {   // L1: a1 = relu(S1 @ W1t + b1)
        f32x4 acc[4] = {};
        for (int k0 = 0; k0 < 64; k0 += 32) {
            half8 a = *(const half8*)&S1[(rbase + lr) * P_S1 + k0 + lkb];
            #pragma unroll
            for (int nt = 0; nt < 4; ++nt) {
                half8 bf = *(const half8*)&W1t[(cbase + nt * 16 + lr) * 64 + k0 + lkb];
                acc[nt] = __builtin_amdgcn_mfma_f32_16x16x32_f16(a, bf, acc[nt], 0, 0, 0);
            }
        }
        #pragma unroll
        for (int nt = 0; nt < 4; ++nt) {
            int col = cbase + nt * 16 + lr;
            float bb = b1[col];
            #pragma unroll
            for (int j = 0; j < 4; ++j)
                a1[(rbase + rj + j) * P_A + col] = (_Float16)fmaxf(acc[nt][j] + bb, 0.f);
        }
    }
    __syncthreads();

    for (int i = tid; i < 64 * 160; i += 512) {
        int r = i / 160, k = i % 160;
        float v = 0.f;
        if (k < 128) {
            v = (float)a1[r * P_A + k];
            #pragma unroll
            for (int d = 0; d < DM; ++d) v += (float)a1[edg[r * DM + d] * P_A + k];
        } else if (k < 134) {
            v = bond[r * FB + (k - 128)];
        }
        S23[r * P_S23 + k] = (_Float16)v;
    }
    __syncthreads();

    f32x4 acc2[4] = {};
    for (int k0 = 0; k0 < 160; k0 += 32) {
        half8 a = *(const half8*)&S23[(rbase + lr) * P_S23 + k0 + lkb];
        #pragma unroll
        for (int nt = 0; nt < 4; ++nt) {
            half8 bf = *(const half8*)&W2t[(cbase + nt * 16 + lr) * 160 + k0 + lkb];
            acc2[nt] = __builtin_amdgcn_mfma_f32_16x16x32_f16(a, bf, acc2[nt], 0, 0, 0);
        }
    }
    __syncthreads();

    #pragma unroll
    for (int nt = 0; nt < 4; ++nt) {
        int col = cbase + nt * 16 + lr;
        float bb = b2[col];
        #pragma unroll
        for (int j = 0; j < 4; ++j)
            S23[(rbase + rj + j) * P_S23 + col] = (_Float16)fmaxf(acc2[nt][j] + bb, 0.f);
    }
    for (int i = tid; i < 64 * 32; i += 512) {
        int r = i >> 5, k = 128 + (i & 31);
        S23[r * P_S23 + k] = (k < 134) ? (_Float16)bond[r * FB + (k - 128)] : (_Float16)0.f;
    }
    __syncthreads();

    {   // L3: fpm = sum_rows tanh(S3 @ Wot + bo)
        f32x4 acc3[4] = {};
        for (int k0 = 0; k0 < 160; k0 += 32) {
            half8 a = *(const half8*)&S23[(rbase + lr) * P_S23 + k0 + lkb];
            #pragma unroll
            for (int nt = 0; nt < 4; ++nt) {
                half8 bf = *(const half8*)&Wot[(cbase + nt * 16 + lr) * 160 + k0 + lkb];
                acc3[nt] = __builtin_amdgcn_mfma_f32_16x16x32_f16(a, bf, acc3[nt], 0, 0, 0);
            }
        }
        #pragma unroll
        for (int nt = 0; nt < 4; ++nt) {
            int col = cbase + nt * 16 + lr;
            float bb = bo[col];
            float s = 0.f;
            #pragma unroll
            for (int j = 0; j < 4; ++j) s += tanhf(acc3[nt][j] + bb);
            s += __shfl_xor(s, 16);
            s += __shfl_xor(s, 32);
            if (lane < 16) red[rw * 128 + col] = s;
        }
    }
    __syncthreads();

    if (tid < 128)       fcb[tid] = red[tid] + red[128 + tid] + red[256 + tid] + red[384 + tid];
    else if (tid < 256)  fcb[tid] = fpp[b * 128 + (tid - 128)];
    __syncthreads();
    if (tid < 100) {
        float acc = bf1[tid];
        for (int k = 0; k < 256; ++k) acc = fmaf(fcb[k], Wf1[k * 100 + tid], acc);
        fcb[256 + tid] = acc;
    }
    __syncthreads();
    if (tid < 100) {
        float acc = bf2[tid];
        for (int k = 0; k < 100; ++k) acc = fmaf(fcb[256 + k], Wf2[k * 100 + tid], acc);
        fcb[356 + tid] = acc;
    }
    __syncthreads();
    if (tid < 64) {
        float v = fcb[356 + tid] * Wout[tid];
        if (tid + 64 < 100) v += fcb[356 + tid + 64] * Wout[tid + 64];
        #pragma unroll
        for (int off = 32; off > 0; off >>= 1) v += __shfl_down(v, off);
        if (tid == 0) out[b] = 1.f / (1.f + expf(-(v + bout[0])));
    }
}

extern "C" void kernel_launch(void* const* d_in, const int* in_sizes, int n_in,
                              void* d_out, int out_size, void* d_ws, size_t ws_size,
                              hipStream_t stream) {
    const float* m_atoms = (const float*)d_in[0];
    const float* m_bonds = (const float*)d_in[1];
    const int*   m_edges = (const int*)  d_in[2];
    const float* p_atoms = (const float*)d_in[3];
    const int*   p_edges = (const int*)  d_in[4];
    const float* W1   = (const float*)d_in[5];  const float* b1   = (const float*)d_in[6];
    const float* W2   = (const float*)d_in[7];  const float* b2   = (const float*)d_in[8];
    const float* Wp1  = (const float*)d_in[9];  const float* bp1  = (const float*)d_in[10];
    const float* Wp2  = (const float*)d_in[11]; const float* bp2  = (const float*)d_in[12];
    const float* Wo   = (const float*)d_in[13]; const float* bo   = (const float*)d_in[14];
    const float* Wop  = (const float*)d_in[15]; const float* bop  = (const float*)d_in[16];
    const float* Wf1  = (const float*)d_in[17]; const float* bf1  = (const float*)d_in[18];
    const float* Wf2  = (const float*)d_in[19]; const float* bf2  = (const float*)d_in[20];
    const float* Wout = (const float*)d_in[21]; const float* bout = (const float*)d_in[22];

    float* ws   = (float*)d_ws;
    float* fpp  = ws + OFF_FPP;
    _Float16* z1  = (_Float16*)(ws + OFF_Z1);
    _Float16* z2  = (_Float16*)(ws + OFF_Z2);
    _Float16* w16 = (_Float16*)(ws + OFF_W16);

    hipMemsetAsync(fpp, 0, (size_t)B * 128 * sizeof(float), stream);
    k_prep<<<dim3((W16_TOT + 255) / 256), 256, 0, stream>>>(
        Wp1, Wp2, Wop, W1, W2, Wo, bp1, bp2, w16);

    k_zp1 <<<dim3(B * NP / 32), 256, 0, stream>>>(p_atoms, w16 + W16_WT1, z1);
    k_zp2f<<<dim3(B * NP / 64), 256, 0, stream>>>(z1, p_edges, w16 + W16_BP1,
                                                  w16 + W16_WT2, z2);
    k_pof <<<dim3(B * NP / 64), 256, 0, stream>>>(z2, p_edges, w16 + W16_BP2,
                                                  w16 + W16_WTOP, bop, fpp);

    k_mol <<<dim3(B), 512, 0, stream>>>(m_atoms, m_bonds, m_edges,
                                        w16 + W16_MW1T, w16 + W16_MW2T, w16 + W16_MWOT,
                                        b1, b2, bo, fpp,
                                        Wf1, bf1, Wf2, bf2, Wout, bout, (float*)d_out);
}